// Round 2
// baseline (438.428 us; speedup 1.0000x reference)
//
#include <hip/hip_runtime.h>
#include <math.h>

#define NF 128
#define NH 256
#define GEMM_ROWS 32

// ---------------- graph prep ----------------

__global__ void init_kernel(int* __restrict__ deg, int* __restrict__ fill, int N) {
    int i = blockIdx.x * blockDim.x + threadIdx.x;
    if (i < N) { deg[i] = 1; fill[i] = 0; }   // 1 = self-loop
}

__global__ void count_kernel(const int* __restrict__ dst, int* __restrict__ deg, int E) {
    int i = blockIdx.x * blockDim.x + threadIdx.x;
    if (i < E) atomicAdd(&deg[dst[i]], 1);
}

__global__ void dis_kernel(const int* __restrict__ deg, float* __restrict__ dis, int N) {
    int i = blockIdx.x * blockDim.x + threadIdx.x;
    if (i < N) dis[i] = rsqrtf((float)deg[i]);
}

// exclusive scan of (deg[i]-1) -> rowptr (block-local), block sums out
__global__ void scan1_kernel(const int* __restrict__ deg, int* __restrict__ rowptr,
                             int* __restrict__ bsums, int N) {
    __shared__ int sm[256];
    int i = blockIdx.x * 256 + threadIdx.x;
    int v = (i < N) ? (deg[i] - 1) : 0;
    sm[threadIdx.x] = v;
    __syncthreads();
    int s = v;
    for (int off = 1; off < 256; off <<= 1) {
        int t = 0;
        if ((int)threadIdx.x >= off) t = sm[threadIdx.x - off];
        __syncthreads();
        s += t;
        sm[threadIdx.x] = s;
        __syncthreads();
    }
    if (i < N) rowptr[i] = s - v;             // exclusive within block
    if (threadIdx.x == 255) bsums[blockIdx.x] = s;
}

// scan block sums (NB <= 256), single block
__global__ void scan2_kernel(const int* __restrict__ bsums, int* __restrict__ boff, int NB) {
    __shared__ int sm[256];
    int t = threadIdx.x;
    int v = (t < NB) ? bsums[t] : 0;
    sm[t] = v;
    __syncthreads();
    int s = v;
    for (int off = 1; off < 256; off <<= 1) {
        int x = 0;
        if (t >= off) x = sm[t - off];
        __syncthreads();
        s += x;
        sm[t] = s;
        __syncthreads();
    }
    boff[t] = s - v;                          // exclusive block offsets
}

__global__ void scan3_kernel(int* __restrict__ rowptr, const int* __restrict__ boff, int N, int E) {
    int i = blockIdx.x * 256 + threadIdx.x;
    if (i < N) rowptr[i] += boff[blockIdx.x];
    if (blockIdx.x == 0 && threadIdx.x == 0) rowptr[N] = E;
}

__global__ void fill_kernel(const int* __restrict__ src, const int* __restrict__ dst,
                            const int* __restrict__ rowptr, int* __restrict__ fill,
                            const float* __restrict__ dis,
                            int* __restrict__ csr_src, float* __restrict__ csr_norm, int E) {
    int i = blockIdx.x * blockDim.x + threadIdx.x;
    if (i >= E) return;
    int s = src[i], d = dst[i];
    int pos = atomicAdd(&fill[d], 1);
    int idx = rowptr[d] + pos;
    csr_src[idx] = s;
    csr_norm[idx] = dis[s] * dis[d];
}

// ---------------- GEMM: Out[N,256] = X[N,K] @ W[K,256] (no bias) ----------------

template <int K>
__global__ __launch_bounds__(256) void gemm_kernel(const float* __restrict__ X,
                                                   const float* __restrict__ W,
                                                   float* __restrict__ Out, int N) {
    __shared__ float xs[GEMM_ROWS][K];
    int tid = threadIdx.x;
    int row0 = blockIdx.x * GEMM_ROWS;

    const float4* X4 = reinterpret_cast<const float4*>(X);
    constexpr int TOT4 = GEMM_ROWS * K / 4;
    for (int idx = tid; idx < TOT4; idx += 256) {
        int r  = idx / (K / 4);
        int c4 = idx % (K / 4);
        int gr = row0 + r;
        float4 v;
        if (gr < N) v = X4[(size_t)gr * (K / 4) + c4];
        else        v = make_float4(0.f, 0.f, 0.f, 0.f);
        *reinterpret_cast<float4*>(&xs[r][c4 * 4]) = v;
    }
    __syncthreads();

    int cg = tid & 63;          // 64 col groups of 4 -> 256 cols
    int rg = (tid >> 6) * 8;    // 4 row groups of 8 -> 32 rows

    float acc[8][4];
#pragma unroll
    for (int r = 0; r < 8; ++r)
#pragma unroll
        for (int c = 0; c < 4; ++c) acc[r][c] = 0.f;

    const float4* W4 = reinterpret_cast<const float4*>(W);   // [K][64] float4

    for (int k = 0; k < K; k += 4) {
        float4 xr[8];
#pragma unroll
        for (int r = 0; r < 8; ++r)
            xr[r] = *reinterpret_cast<const float4*>(&xs[rg + r][k]);
#pragma unroll
        for (int kk = 0; kk < 4; ++kk) {
            float4 wv = W4[(size_t)(k + kk) * 64 + cg];
#pragma unroll
            for (int r = 0; r < 8; ++r) {
                float xv = (kk == 0) ? xr[r].x : (kk == 1) ? xr[r].y : (kk == 2) ? xr[r].z : xr[r].w;
                acc[r][0] = fmaf(xv, wv.x, acc[r][0]);
                acc[r][1] = fmaf(xv, wv.y, acc[r][1]);
                acc[r][2] = fmaf(xv, wv.z, acc[r][2]);
                acc[r][3] = fmaf(xv, wv.w, acc[r][3]);
            }
        }
    }

    float4* O4 = reinterpret_cast<float4*>(Out);
#pragma unroll
    for (int r = 0; r < 8; ++r) {
        int gr = row0 + rg + r;
        if (gr < N) {
            float4 o = make_float4(acc[r][0], acc[r][1], acc[r][2], acc[r][3]);
            O4[(size_t)gr * 64 + cg] = o;
        }
    }
}

// ------------- aggregation over 256 features: wave per node, lane owns 4 feats -------------
// out[n] = relu?( sum_{e in in(n)} H[src_e]*norm_e + H[n]*dis[n]^2 + bias )
// FUSE: instead of storing, dot with W3 -> outC[n]

template <bool RELU, bool FUSE>
__global__ __launch_bounds__(256) void agg_kernel(const float* __restrict__ H,
                                                  const int* __restrict__ rowptr,
                                                  const int* __restrict__ csr_src,
                                                  const float* __restrict__ csr_norm,
                                                  const float* __restrict__ dis,
                                                  const float* __restrict__ bias,
                                                  float* __restrict__ Out,
                                                  const float* __restrict__ W3,
                                                  float* __restrict__ outC, int N) {
    int lane = threadIdx.x & 63;
    int node = blockIdx.x * (blockDim.x >> 6) + (threadIdx.x >> 6);
    if (node >= N) return;

    const float4* H4 = reinterpret_cast<const float4*>(H);
    float dn = dis[node];
    float4 sv = H4[(size_t)node * 64 + lane];
    float n0 = dn * dn;
    float ax = sv.x * n0, ay = sv.y * n0, az = sv.z * n0, aw = sv.w * n0;

    int start = rowptr[node], end = rowptr[node + 1];
    for (int j = start; j < end; ++j) {
        int s   = csr_src[j];
        float m = csr_norm[j];
        float4 v = H4[(size_t)s * 64 + lane];
        ax = fmaf(v.x, m, ax);
        ay = fmaf(v.y, m, ay);
        az = fmaf(v.z, m, az);
        aw = fmaf(v.w, m, aw);
    }

    float4 b = reinterpret_cast<const float4*>(bias)[lane];
    ax += b.x; ay += b.y; az += b.z; aw += b.w;
    if (RELU) {
        ax = fmaxf(ax, 0.f); ay = fmaxf(ay, 0.f);
        az = fmaxf(az, 0.f); aw = fmaxf(aw, 0.f);
    }

    if (!FUSE) {
        reinterpret_cast<float4*>(Out)[(size_t)node * 64 + lane] =
            make_float4(ax, ay, az, aw);
    } else {
        float4 w = reinterpret_cast<const float4*>(W3)[lane];
        float d = ax * w.x + ay * w.y + az * w.z + aw * w.w;
#pragma unroll
        for (int off = 32; off > 0; off >>= 1) d += __shfl_down(d, off);
        if (lane == 0) outC[node] = d;
    }
}

// ------------- final 1-wide aggregation + sigmoid -------------

__global__ void agg1_kernel(const float* __restrict__ c, const int* __restrict__ rowptr,
                            const int* __restrict__ csr_src, const float* __restrict__ csr_norm,
                            const float* __restrict__ dis, const float* __restrict__ b3,
                            float* __restrict__ out, int N) {
    int i = blockIdx.x * blockDim.x + threadIdx.x;
    if (i >= N) return;
    float dn = dis[i];
    float acc = c[i] * dn * dn;
    int start = rowptr[i], end = rowptr[i + 1];
    for (int j = start; j < end; ++j) acc += c[csr_src[j]] * csr_norm[j];
    acc += b3[0];
    out[i] = 1.0f / (1.0f + expf(-acc));
}

// ---------------- launch ----------------

extern "C" void kernel_launch(void* const* d_in, const int* in_sizes, int n_in,
                              void* d_out, int out_size, void* d_ws, size_t ws_size,
                              hipStream_t stream) {
    const float* x  = (const float*)d_in[0];
    const int*   ei = (const int*)d_in[1];
    const float* W1 = (const float*)d_in[2];
    const float* b1 = (const float*)d_in[3];
    const float* W2 = (const float*)d_in[4];
    const float* b2 = (const float*)d_in[5];
    const float* W3 = (const float*)d_in[6];
    const float* b3 = (const float*)d_in[7];

    int N = in_sizes[0] / NF;      // 50000
    int E = in_sizes[1] / 2;       // 640000
    const int* src = ei;
    const int* dst = ei + E;

    // workspace carve (all 256B aligned)
    char* ws = (char*)d_ws;
    auto alloc = [&](size_t bytes) -> void* {
        void* p = (void*)ws;
        ws += (bytes + 255) & ~(size_t)255;
        return p;
    };
    int*   deg      = (int*)alloc((size_t)N * 4);
    int*   fill     = (int*)alloc((size_t)N * 4);
    float* dis      = (float*)alloc((size_t)N * 4);
    int*   rowptr   = (int*)alloc((size_t)(N + 1) * 4);
    int*   bsums    = (int*)alloc(1024);
    int*   boff     = (int*)alloc(1024);
    int*   csr_src  = (int*)alloc((size_t)E * 4);
    float* csr_norm = (float*)alloc((size_t)E * 4);
    float* bufA     = (float*)alloc((size_t)N * NH * 4);
    float* bufB     = (float*)alloc((size_t)N * NH * 4);
    float* bufC     = (float*)alloc((size_t)N * 4);
    (void)ws_size; (void)n_in; (void)out_size;

    int nbN = (N + 255) / 256;           // 196
    int nbE = (E + 255) / 256;           // 2500

    init_kernel<<<nbN, 256, 0, stream>>>(deg, fill, N);
    count_kernel<<<nbE, 256, 0, stream>>>(dst, deg, E);
    dis_kernel<<<nbN, 256, 0, stream>>>(deg, dis, N);
    scan1_kernel<<<nbN, 256, 0, stream>>>(deg, rowptr, bsums, N);
    scan2_kernel<<<1, 256, 0, stream>>>(bsums, boff, nbN);
    scan3_kernel<<<nbN, 256, 0, stream>>>(rowptr, boff, N, E);
    fill_kernel<<<nbE, 256, 0, stream>>>(src, dst, rowptr, fill, dis, csr_src, csr_norm, E);

    int nbG = (N + GEMM_ROWS - 1) / GEMM_ROWS;   // 1563
    int nbA = (N + 3) / 4;                        // 12500 (4 waves/block)

    // layer 1: A = x @ W1 ; B = relu(agg(A) + b1)
    gemm_kernel<NF><<<nbG, 256, 0, stream>>>(x, W1, bufA, N);
    agg_kernel<true, false><<<nbA, 256, 0, stream>>>(bufA, rowptr, csr_src, csr_norm,
                                                     dis, b1, bufB, nullptr, nullptr, N);
    // layer 2: A = B @ W2 ; fused: C = relu(agg(A) + b2) @ W3
    gemm_kernel<NH><<<nbG, 256, 0, stream>>>(bufB, W2, bufA, N);
    agg_kernel<true, true><<<nbA, 256, 0, stream>>>(bufA, rowptr, csr_src, csr_norm,
                                                    dis, b2, nullptr, W3, bufC, N);
    // layer 3: out = sigmoid(agg(C) + b3)
    agg1_kernel<<<nbN, 256, 0, stream>>>(bufC, rowptr, csr_src, csr_norm, dis, b3,
                                         (float*)d_out, N);
}

// Round 6
// 391.598 us; speedup vs baseline: 1.1196x; 1.1196x over previous
//
#include <hip/hip_runtime.h>
#include <math.h>

#define NF 128
#define NH 256
#define GEMM_ROWS 32

typedef unsigned short ushort_t;

__device__ __forceinline__ float b2f(ushort_t h) {
    return __uint_as_float((unsigned int)h << 16);
}
__device__ __forceinline__ ushort_t f2b(float f) {
    unsigned int u = __float_as_uint(f);
    unsigned int r = (u + 0x7FFF + ((u >> 16) & 1)) >> 16;   // RNE
    return (ushort_t)r;
}

// ---------------- graph prep ----------------

__global__ void init_kernel(int* __restrict__ deg, int* __restrict__ fill, int N) {
    int i = blockIdx.x * blockDim.x + threadIdx.x;
    if (i < N) { deg[i] = 1; fill[i] = 0; }   // 1 = self-loop
}

__global__ void count_kernel(const int* __restrict__ dst, int* __restrict__ deg, int E) {
    int i = blockIdx.x * blockDim.x + threadIdx.x;
    if (i < E) atomicAdd(&deg[dst[i]], 1);
}

__global__ void dis_kernel(const int* __restrict__ deg, float* __restrict__ dis, int N) {
    int i = blockIdx.x * blockDim.x + threadIdx.x;
    if (i < N) dis[i] = rsqrtf((float)deg[i]);
}

__global__ void scan1_kernel(const int* __restrict__ deg, int* __restrict__ rowptr,
                             int* __restrict__ bsums, int N) {
    __shared__ int sm[256];
    int i = blockIdx.x * 256 + threadIdx.x;
    int v = (i < N) ? (deg[i] - 1) : 0;
    sm[threadIdx.x] = v;
    __syncthreads();
    int s = v;
    for (int off = 1; off < 256; off <<= 1) {
        int t = 0;
        if ((int)threadIdx.x >= off) t = sm[threadIdx.x - off];
        __syncthreads();
        s += t;
        sm[threadIdx.x] = s;
        __syncthreads();
    }
    if (i < N) rowptr[i] = s - v;
    if (threadIdx.x == 255) bsums[blockIdx.x] = s;
}

__global__ void scan2_kernel(const int* __restrict__ bsums, int* __restrict__ boff, int NB) {
    __shared__ int sm[256];
    int t = threadIdx.x;
    int v = (t < NB) ? bsums[t] : 0;
    sm[t] = v;
    __syncthreads();
    int s = v;
    for (int off = 1; off < 256; off <<= 1) {
        int x = 0;
        if (t >= off) x = sm[t - off];
        __syncthreads();
        s += x;
        sm[t] = s;
        __syncthreads();
    }
    boff[t] = s - v;
}

__global__ void scan3_kernel(int* __restrict__ rowptr, const int* __restrict__ boff, int N, int E) {
    int i = blockIdx.x * 256 + threadIdx.x;
    if (i < N) rowptr[i] += boff[blockIdx.x];
    if (blockIdx.x == 0 && threadIdx.x == 0) rowptr[N] = E;
}

__global__ void fill_kernel(const int* __restrict__ src, const int* __restrict__ dst,
                            const int* __restrict__ rowptr, int* __restrict__ fill,
                            const float* __restrict__ dis,
                            int* __restrict__ csr_src, float* __restrict__ csr_norm, int E) {
    int i = blockIdx.x * blockDim.x + threadIdx.x;
    if (i >= E) return;
    int s = src[i], d = dst[i];
    int pos = atomicAdd(&fill[d], 1);
    int idx = rowptr[d] + pos;
    csr_src[idx] = s;
    csr_norm[idx] = dis[s] * dis[d];
}

// ------------- aggregation, f32 input, 128 features: wave/node, lane owns float2 -------------
// AX[n] = sum_{e in in(n)} X[src_e]*norm_e + X[n]*dis[n]^2

__global__ __launch_bounds__(256) void aggf32_128_kernel(const float* __restrict__ X,
                                                         const int* __restrict__ rowptr,
                                                         const int* __restrict__ csr_src,
                                                         const float* __restrict__ csr_norm,
                                                         const float* __restrict__ dis,
                                                         float* __restrict__ Out, int N) {
    int lane = threadIdx.x & 63;
    int node = blockIdx.x * (blockDim.x >> 6) + (threadIdx.x >> 6);
    if (node >= N) return;

    const float2* X2 = reinterpret_cast<const float2*>(X);
    float dn = dis[node];
    float n0 = dn * dn;
    float2 sv = X2[(size_t)node * 64 + lane];
    float ax = sv.x * n0, ay = sv.y * n0;

    int start = rowptr[node], end = rowptr[node + 1];
    for (int j = start; j < end; ++j) {
        int s   = csr_src[j];
        float m = csr_norm[j];
        float2 v = X2[(size_t)s * 64 + lane];
        ax = fmaf(v.x, m, ax);
        ay = fmaf(v.y, m, ay);
    }
    reinterpret_cast<float2*>(Out)[(size_t)node * 64 + lane] = make_float2(ax, ay);
}

// ------------- aggregation, bf16 input, 256 features: wave/node, lane owns 4 bf16 -------------

__global__ __launch_bounds__(256) void aggbf16_256_kernel(const ushort_t* __restrict__ H,
                                                          const int* __restrict__ rowptr,
                                                          const int* __restrict__ csr_src,
                                                          const float* __restrict__ csr_norm,
                                                          const float* __restrict__ dis,
                                                          float* __restrict__ Out, int N) {
    int lane = threadIdx.x & 63;
    int node = blockIdx.x * (blockDim.x >> 6) + (threadIdx.x >> 6);
    if (node >= N) return;

    const ushort4* H4 = reinterpret_cast<const ushort4*>(H);
    float dn = dis[node];
    float n0 = dn * dn;
    ushort4 sv = H4[(size_t)node * 64 + lane];
    float ax = b2f(sv.x) * n0, ay = b2f(sv.y) * n0;
    float az = b2f(sv.z) * n0, aw = b2f(sv.w) * n0;

    int start = rowptr[node], end = rowptr[node + 1];
    for (int j = start; j < end; ++j) {
        int s   = csr_src[j];
        float m = csr_norm[j];
        ushort4 v = H4[(size_t)s * 64 + lane];
        ax = fmaf(b2f(v.x), m, ax);
        ay = fmaf(b2f(v.y), m, ay);
        az = fmaf(b2f(v.z), m, az);
        aw = fmaf(b2f(v.w), m, aw);
    }
    reinterpret_cast<float4*>(Out)[(size_t)node * 64 + lane] =
        make_float4(ax, ay, az, aw);
}

// ---------------- GEMM: [N,K] @ [K,256] with fused epilogues ----------------
// MODE 1: out = bf16( relu(acc + bias) )          -> OutB [N,256] bf16
// MODE 2: out = relu(acc + bias) . W3             -> OutF [N] f32

template <int K, int MODE>
__global__ __launch_bounds__(256) void gemm_kernel(const float* __restrict__ X,
                                                   const float* __restrict__ W,
                                                   const float* __restrict__ bias,
                                                   const float* __restrict__ W3,
                                                   float* __restrict__ OutF,
                                                   ushort_t* __restrict__ OutB, int N) {
    __shared__ float xs[GEMM_ROWS][K];
    int tid = threadIdx.x;
    int row0 = blockIdx.x * GEMM_ROWS;

    const float4* X4 = reinterpret_cast<const float4*>(X);
    constexpr int TOT4 = GEMM_ROWS * K / 4;
    for (int idx = tid; idx < TOT4; idx += 256) {
        int r  = idx / (K / 4);
        int c4 = idx % (K / 4);
        int gr = row0 + r;
        float4 v;
        if (gr < N) v = X4[(size_t)gr * (K / 4) + c4];
        else        v = make_float4(0.f, 0.f, 0.f, 0.f);
        *reinterpret_cast<float4*>(&xs[r][c4 * 4]) = v;
    }
    __syncthreads();

    int cg = tid & 63;          // 64 col groups of 4 -> 256 cols
    int rg = (tid >> 6) * 8;    // 4 row groups of 8 -> 32 rows

    float acc[8][4];
#pragma unroll
    for (int r = 0; r < 8; ++r)
#pragma unroll
        for (int c = 0; c < 4; ++c) acc[r][c] = 0.f;

    const float4* W4 = reinterpret_cast<const float4*>(W);   // [K][64] float4

    for (int k = 0; k < K; k += 4) {
        float4 xr[8];
#pragma unroll
        for (int r = 0; r < 8; ++r)
            xr[r] = *reinterpret_cast<const float4*>(&xs[rg + r][k]);
#pragma unroll
        for (int kk = 0; kk < 4; ++kk) {
            float4 wv = W4[(size_t)(k + kk) * 64 + cg];
#pragma unroll
            for (int r = 0; r < 8; ++r) {
                float xv = (kk == 0) ? xr[r].x : (kk == 1) ? xr[r].y : (kk == 2) ? xr[r].z : xr[r].w;
                acc[r][0] = fmaf(xv, wv.x, acc[r][0]);
                acc[r][1] = fmaf(xv, wv.y, acc[r][1]);
                acc[r][2] = fmaf(xv, wv.z, acc[r][2]);
                acc[r][3] = fmaf(xv, wv.w, acc[r][3]);
            }
        }
    }

    float4 b = reinterpret_cast<const float4*>(bias)[cg];

    if (MODE == 1) {
#pragma unroll
        for (int r = 0; r < 8; ++r) {
            int gr = row0 + rg + r;
            if (gr < N) {
                ushort4 o;
                o.x = f2b(fmaxf(acc[r][0] + b.x, 0.f));
                o.y = f2b(fmaxf(acc[r][1] + b.y, 0.f));
                o.z = f2b(fmaxf(acc[r][2] + b.z, 0.f));
                o.w = f2b(fmaxf(acc[r][3] + b.w, 0.f));
                reinterpret_cast<ushort4*>(OutB)[(size_t)gr * 64 + cg] = o;
            }
        }
    } else {
        float4 w3 = reinterpret_cast<const float4*>(W3)[cg];
#pragma unroll
        for (int r = 0; r < 8; ++r) {
            float p = fmaxf(acc[r][0] + b.x, 0.f) * w3.x
                    + fmaxf(acc[r][1] + b.y, 0.f) * w3.y
                    + fmaxf(acc[r][2] + b.z, 0.f) * w3.z
                    + fmaxf(acc[r][3] + b.w, 0.f) * w3.w;
#pragma unroll
            for (int off = 32; off > 0; off >>= 1) p += __shfl_down(p, off);
            int gr = row0 + rg + r;
            if (cg == 0 && gr < N) OutF[gr] = p;
        }
    }
}

// ------------- final 1-wide aggregation + sigmoid -------------

__global__ void agg1_kernel(const float* __restrict__ c, const int* __restrict__ rowptr,
                            const int* __restrict__ csr_src, const float* __restrict__ csr_norm,
                            const float* __restrict__ dis, const float* __restrict__ b3,
                            float* __restrict__ out, int N) {
    int i = blockIdx.x * blockDim.x + threadIdx.x;
    if (i >= N) return;
    float dn = dis[i];
    float acc = c[i] * dn * dn;
    int start = rowptr[i], end = rowptr[i + 1];
    for (int j = start; j < end; ++j) acc += c[csr_src[j]] * csr_norm[j];
    acc += b3[0];
    out[i] = 1.0f / (1.0f + expf(-acc));
}

// ---------------- launch ----------------

extern "C" void kernel_launch(void* const* d_in, const int* in_sizes, int n_in,
                              void* d_out, int out_size, void* d_ws, size_t ws_size,
                              hipStream_t stream) {
    const float* x  = (const float*)d_in[0];
    const int*   ei = (const int*)d_in[1];
    const float* W1 = (const float*)d_in[2];
    const float* b1 = (const float*)d_in[3];
    const float* W2 = (const float*)d_in[4];
    const float* b2 = (const float*)d_in[5];
    const float* W3 = (const float*)d_in[6];
    const float* b3 = (const float*)d_in[7];

    int N = in_sizes[0] / NF;      // 50000
    int E = in_sizes[1] / 2;       // 640000
    const int* src = ei;
    const int* dst = ei + E;

    char* ws = (char*)d_ws;
    auto alloc = [&](size_t bytes) -> void* {
        void* p = (void*)ws;
        ws += (bytes + 255) & ~(size_t)255;
        return p;
    };
    int*      deg      = (int*)alloc((size_t)N * 4);
    int*      fill     = (int*)alloc((size_t)N * 4);
    float*    dis      = (float*)alloc((size_t)N * 4);
    int*      rowptr   = (int*)alloc((size_t)(N + 1) * 4);
    int*      bsums    = (int*)alloc(1024);
    int*      boff     = (int*)alloc(1024);
    int*      csr_src  = (int*)alloc((size_t)E * 4);
    float*    csr_norm = (float*)alloc((size_t)E * 4);
    float*    bufAX    = (float*)alloc((size_t)N * NF * 4);   // Â·X      [N,128] f32
    ushort_t* bufH1    = (ushort_t*)alloc((size_t)N * NH * 2); // H1      [N,256] bf16
    float*    bufG     = (float*)alloc((size_t)N * NH * 4);   // Â·H1     [N,256] f32
    float*    bufC     = (float*)alloc((size_t)N * 4);        // H2·W3    [N]     f32
    (void)ws_size; (void)n_in; (void)out_size;

    int nbN = (N + 255) / 256;           // 196
    int nbE = (E + 255) / 256;           // 2500

    init_kernel<<<nbN, 256, 0, stream>>>(deg, fill, N);
    count_kernel<<<nbE, 256, 0, stream>>>(dst, deg, E);
    dis_kernel<<<nbN, 256, 0, stream>>>(deg, dis, N);
    scan1_kernel<<<nbN, 256, 0, stream>>>(deg, rowptr, bsums, N);
    scan2_kernel<<<1, 256, 0, stream>>>(bsums, boff, nbN);
    scan3_kernel<<<nbN, 256, 0, stream>>>(rowptr, boff, N, E);
    fill_kernel<<<nbE, 256, 0, stream>>>(src, dst, rowptr, fill, dis, csr_src, csr_norm, E);

    int nbG = (N + GEMM_ROWS - 1) / GEMM_ROWS;   // 1563
    int nbA = (N + 3) / 4;                        // 12500 (4 waves/block)

    // layer 1: AX = Â·X (128-wide, f32) ; H1 = bf16(relu(AX@W1 + b1))
    aggf32_128_kernel<<<nbA, 256, 0, stream>>>(x, rowptr, csr_src, csr_norm, dis, bufAX, N);
    gemm_kernel<NF, 1><<<nbG, 256, 0, stream>>>(bufAX, W1, b1, nullptr, nullptr, bufH1, N);
    // layer 2: G = Â·H1 (256-wide, bf16 gather) ; C = relu(G@W2 + b2)·W3
    aggbf16_256_kernel<<<nbA, 256, 0, stream>>>(bufH1, rowptr, csr_src, csr_norm, dis, bufG, N);
    gemm_kernel<NH, 2><<<nbG, 256, 0, stream>>>(bufG, W2, b2, W3, bufC, nullptr, N);
    // layer 3: out = sigmoid(Â·C + b3)
    agg1_kernel<<<nbN, 256, 0, stream>>>(bufC, rowptr, csr_src, csr_norm, dis, b3,
                                         (float*)d_out, N);
}

// Round 7
// 288.864 us; speedup vs baseline: 1.5178x; 1.3556x over previous
//
#include <hip/hip_runtime.h>
#include <math.h>

#define NF 128
#define NH 256

typedef unsigned short ushort_t;
typedef __attribute__((ext_vector_type(8))) short bf16x8;
typedef __attribute__((ext_vector_type(4))) float f32x4;

__device__ __forceinline__ float b2f(ushort_t h) {
    return __uint_as_float((unsigned int)h << 16);
}
__device__ __forceinline__ ushort_t f2b(float f) {
    unsigned int u = __float_as_uint(f);
    unsigned int r = (u + 0x7FFF + ((u >> 16) & 1)) >> 16;   // RNE
    return (ushort_t)r;
}

// ---------------- graph prep ----------------

__global__ void init_kernel(int* __restrict__ deg, int* __restrict__ fill, int N) {
    int i = blockIdx.x * blockDim.x + threadIdx.x;
    if (i < N) { deg[i] = 1; fill[i] = 0; }   // 1 = self-loop
}

__global__ void count_kernel(const int* __restrict__ dst, int* __restrict__ deg, int E) {
    int i = blockIdx.x * blockDim.x + threadIdx.x;
    if (i < E) atomicAdd(&deg[dst[i]], 1);
}

__global__ void dis_kernel(const int* __restrict__ deg, float* __restrict__ dis, int N) {
    int i = blockIdx.x * blockDim.x + threadIdx.x;
    if (i < N) dis[i] = rsqrtf((float)deg[i]);
}

__global__ void scan1_kernel(const int* __restrict__ deg, int* __restrict__ rowptr,
                             int* __restrict__ bsums, int N) {
    __shared__ int sm[256];
    int i = blockIdx.x * 256 + threadIdx.x;
    int v = (i < N) ? (deg[i] - 1) : 0;
    sm[threadIdx.x] = v;
    __syncthreads();
    int s = v;
    for (int off = 1; off < 256; off <<= 1) {
        int t = 0;
        if ((int)threadIdx.x >= off) t = sm[threadIdx.x - off];
        __syncthreads();
        s += t;
        sm[threadIdx.x] = s;
        __syncthreads();
    }
    if (i < N) rowptr[i] = s - v;
    if (threadIdx.x == 255) bsums[blockIdx.x] = s;
}

__global__ void scan2_kernel(const int* __restrict__ bsums, int* __restrict__ boff, int NB) {
    __shared__ int sm[256];
    int t = threadIdx.x;
    int v = (t < NB) ? bsums[t] : 0;
    sm[t] = v;
    __syncthreads();
    int s = v;
    for (int off = 1; off < 256; off <<= 1) {
        int x = 0;
        if (t >= off) x = sm[t - off];
        __syncthreads();
        s += x;
        sm[t] = s;
        __syncthreads();
    }
    boff[t] = s - v;
}

__global__ void scan3_kernel(int* __restrict__ rowptr, const int* __restrict__ boff, int N, int E) {
    int i = blockIdx.x * 256 + threadIdx.x;
    if (i < N) rowptr[i] += boff[blockIdx.x];
    if (blockIdx.x == 0 && threadIdx.x == 0) rowptr[N] = E;
}

__global__ void fill_kernel(const int* __restrict__ src, const int* __restrict__ dst,
                            const int* __restrict__ rowptr, int* __restrict__ fill,
                            const float* __restrict__ dis,
                            int* __restrict__ csr_src, float* __restrict__ csr_norm, int E) {
    int i = blockIdx.x * blockDim.x + threadIdx.x;
    if (i >= E) return;
    int s = src[i], d = dst[i];
    int pos = atomicAdd(&fill[d], 1);
    int idx = rowptr[d] + pos;
    csr_src[idx] = s;
    csr_norm[idx] = dis[s] * dis[d];
}

// ---------------- dtype prep ----------------

// X f32 -> bf16 (8 elements per thread)
__global__ void x2b_kernel(const float* __restrict__ X, ushort_t* __restrict__ Xb, int n8) {
    int i = blockIdx.x * 256 + threadIdx.x;
    if (i >= n8) return;
    const float4* X4 = reinterpret_cast<const float4*>(X);
    float4 a = X4[i * 2], b = X4[i * 2 + 1];
    ushort4 lo, hi;
    lo.x = f2b(a.x); lo.y = f2b(a.y); lo.z = f2b(a.z); lo.w = f2b(a.w);
    hi.x = f2b(b.x); hi.y = f2b(b.y); hi.z = f2b(b.z); hi.w = f2b(b.w);
    reinterpret_cast<ushort4*>(Xb)[i * 2]     = lo;
    reinterpret_cast<ushort4*>(Xb)[i * 2 + 1] = hi;
}

// Pack W [K][256] f32 into MFMA B-fragment layout: [K/32][16 ct][64 lane][8]
// slot (kk,ct,lane,j) <- W[kk*32 + (lane>>4)*8 + j][ct*16 + (lane&15)]
__global__ void packW_kernel(const float* __restrict__ W, ushort_t* __restrict__ Bp, int total) {
    int idx = blockIdx.x * 256 + threadIdx.x;
    if (idx >= total) return;
    int j    = idx & 7;
    int lane = (idx >> 3) & 63;
    int ct   = (idx >> 9) & 15;
    int kk   = idx >> 13;
    int k    = kk * 32 + (lane >> 4) * 8 + j;
    int col  = ct * 16 + (lane & 15);
    Bp[idx] = f2b(W[(size_t)k * 256 + col]);
}

// ------------- aggregation, bf16 in/out, 128 feats: wave/node, lane owns ushort2 -------------

__global__ __launch_bounds__(256) void aggb_128_kernel(const ushort_t* __restrict__ Xb,
                                                       const int* __restrict__ rowptr,
                                                       const int* __restrict__ csr_src,
                                                       const float* __restrict__ csr_norm,
                                                       const float* __restrict__ dis,
                                                       ushort_t* __restrict__ Out, int N) {
    int lane = threadIdx.x & 63;
    int node = blockIdx.x * (blockDim.x >> 6) + (threadIdx.x >> 6);
    if (node >= N) return;

    const ushort2* X2 = reinterpret_cast<const ushort2*>(Xb);
    float dn = dis[node];
    float n0 = dn * dn;
    ushort2 sv = X2[(size_t)node * 64 + lane];
    float ax = b2f(sv.x) * n0, ay = b2f(sv.y) * n0;

    int start = rowptr[node], end = rowptr[node + 1];
    for (int j = start; j < end; ++j) {
        int s   = csr_src[j];
        float m = csr_norm[j];
        ushort2 v = X2[(size_t)s * 64 + lane];
        ax = fmaf(b2f(v.x), m, ax);
        ay = fmaf(b2f(v.y), m, ay);
    }
    ushort2 o; o.x = f2b(ax); o.y = f2b(ay);
    reinterpret_cast<ushort2*>(Out)[(size_t)node * 64 + lane] = o;
}

// ------------- aggregation, bf16 in/out, 256 feats: wave/node, lane owns ushort4 -------------

__global__ __launch_bounds__(256) void aggb_256_kernel(const ushort_t* __restrict__ H,
                                                       const int* __restrict__ rowptr,
                                                       const int* __restrict__ csr_src,
                                                       const float* __restrict__ csr_norm,
                                                       const float* __restrict__ dis,
                                                       ushort_t* __restrict__ Out, int N) {
    int lane = threadIdx.x & 63;
    int node = blockIdx.x * (blockDim.x >> 6) + (threadIdx.x >> 6);
    if (node >= N) return;

    const ushort4* H4 = reinterpret_cast<const ushort4*>(H);
    float dn = dis[node];
    float n0 = dn * dn;
    ushort4 sv = H4[(size_t)node * 64 + lane];
    float ax = b2f(sv.x) * n0, ay = b2f(sv.y) * n0;
    float az = b2f(sv.z) * n0, aw = b2f(sv.w) * n0;

    int start = rowptr[node], end = rowptr[node + 1];
    for (int j = start; j < end; ++j) {
        int s   = csr_src[j];
        float m = csr_norm[j];
        ushort4 v = H4[(size_t)s * 64 + lane];
        ax = fmaf(b2f(v.x), m, ax);
        ay = fmaf(b2f(v.y), m, ay);
        az = fmaf(b2f(v.z), m, az);
        aw = fmaf(b2f(v.w), m, aw);
    }
    ushort4 o;
    o.x = f2b(ax); o.y = f2b(ay); o.z = f2b(az); o.w = f2b(aw);
    reinterpret_cast<ushort4*>(Out)[(size_t)node * 64 + lane] = o;
}

// ---------------- MFMA GEMM: A[N,K] bf16 @ Wp (packed) -> 256 cols ----------------
// 4 waves/block, wave owns 16 rows x 256 cols (16 col-tiles of 16x16x32 MFMA).
// MODE 1: OutB = bf16(relu(acc + bias))  [N,256] row-major
// MODE 2: OutF = relu(acc + bias) . W3   [N] f32

template <int K, int MODE>
__global__ __launch_bounds__(256) void mfma_gemm_kernel(const ushort_t* __restrict__ A,
                                                        const ushort_t* __restrict__ Bp,
                                                        const float* __restrict__ bias,
                                                        const float* __restrict__ W3,
                                                        float* __restrict__ OutF,
                                                        ushort_t* __restrict__ OutB, int N) {
    int wid  = threadIdx.x >> 6;
    int lane = threadIdx.x & 63;
    int row0 = blockIdx.x * 64 + wid * 16;

    int ar = row0 + (lane & 15);
    if (ar >= N) ar = N - 1;                 // clamp; stores are guarded below
    const ushort_t* arow = A + (size_t)ar * K + (lane >> 4) * 8;

    f32x4 acc[16];
#pragma unroll
    for (int ct = 0; ct < 16; ++ct) acc[ct] = (f32x4){0.f, 0.f, 0.f, 0.f};

    const bf16x8* Bv = reinterpret_cast<const bf16x8*>(Bp);
#pragma unroll
    for (int kk = 0; kk < K / 32; ++kk) {
        bf16x8 a = *reinterpret_cast<const bf16x8*>(arow + kk * 32);
        const bf16x8* bbase = Bv + (size_t)kk * 1024 + lane;
#pragma unroll
        for (int ct = 0; ct < 16; ++ct) {
            bf16x8 b = bbase[ct * 64];
            acc[ct] = __builtin_amdgcn_mfma_f32_16x16x32_bf16(a, b, acc[ct], 0, 0, 0);
        }
    }

    // C/D layout: within tile ct, lane holds col = lane&15, rows (lane>>4)*4 + r
    int orow = row0 + (lane >> 4) * 4;
    int ocol = lane & 15;

    if (MODE == 1) {
#pragma unroll
        for (int r = 0; r < 4; ++r) {
            int gr = orow + r;
            if (gr < N) {
#pragma unroll
                for (int ct = 0; ct < 16; ++ct) {
                    float v = fmaxf(acc[ct][r] + bias[ct * 16 + ocol], 0.f);
                    OutB[(size_t)gr * 256 + ct * 16 + ocol] = f2b(v);
                }
            }
        }
    } else {
#pragma unroll
        for (int r = 0; r < 4; ++r) {
            float p = 0.f;
#pragma unroll
            for (int ct = 0; ct < 16; ++ct) {
                float v = fmaxf(acc[ct][r] + bias[ct * 16 + ocol], 0.f);
                p = fmaf(v, W3[ct * 16 + ocol], p);
            }
            p += __shfl_xor(p, 1);
            p += __shfl_xor(p, 2);
            p += __shfl_xor(p, 4);
            p += __shfl_xor(p, 8);
            int gr = orow + r;
            if (ocol == 0 && gr < N) OutF[gr] = p;
        }
    }
}

// ------------- final 1-wide aggregation + sigmoid -------------

__global__ void agg1_kernel(const float* __restrict__ c, const int* __restrict__ rowptr,
                            const int* __restrict__ csr_src, const float* __restrict__ csr_norm,
                            const float* __restrict__ dis, const float* __restrict__ b3,
                            float* __restrict__ out, int N) {
    int i = blockIdx.x * blockDim.x + threadIdx.x;
    if (i >= N) return;
    float dn = dis[i];
    float acc = c[i] * dn * dn;
    int start = rowptr[i], end = rowptr[i + 1];
    for (int j = start; j < end; ++j) acc += c[csr_src[j]] * csr_norm[j];
    acc += b3[0];
    out[i] = 1.0f / (1.0f + expf(-acc));
}

// ---------------- launch ----------------

extern "C" void kernel_launch(void* const* d_in, const int* in_sizes, int n_in,
                              void* d_out, int out_size, void* d_ws, size_t ws_size,
                              hipStream_t stream) {
    const float* x  = (const float*)d_in[0];
    const int*   ei = (const int*)d_in[1];
    const float* W1 = (const float*)d_in[2];
    const float* b1 = (const float*)d_in[3];
    const float* W2 = (const float*)d_in[4];
    const float* b2 = (const float*)d_in[5];
    const float* W3 = (const float*)d_in[6];
    const float* b3 = (const float*)d_in[7];

    int N = in_sizes[0] / NF;      // 50000
    int E = in_sizes[1] / 2;       // 640000
    const int* src = ei;
    const int* dst = ei + E;

    char* ws = (char*)d_ws;
    auto alloc = [&](size_t bytes) -> void* {
        void* p = (void*)ws;
        ws += (bytes + 255) & ~(size_t)255;
        return p;
    };
    int*      deg      = (int*)alloc((size_t)N * 4);
    int*      fill     = (int*)alloc((size_t)N * 4);
    float*    dis      = (float*)alloc((size_t)N * 4);
    int*      rowptr   = (int*)alloc((size_t)(N + 1) * 4);
    int*      bsums    = (int*)alloc(1024);
    int*      boff     = (int*)alloc(1024);
    int*      csr_src  = (int*)alloc((size_t)E * 4);
    float*    csr_norm = (float*)alloc((size_t)E * 4);
    ushort_t* Xb       = (ushort_t*)alloc((size_t)N * NF * 2);   // X bf16        [N,128]
    ushort_t* bufAXb   = (ushort_t*)alloc((size_t)N * NF * 2);   // Â·X bf16      [N,128]
    ushort_t* bufH1    = (ushort_t*)alloc((size_t)N * NH * 2);   // H1 bf16       [N,256]
    ushort_t* bufGb    = (ushort_t*)alloc((size_t)N * NH * 2);   // Â·H1 bf16     [N,256]
    ushort_t* W1p      = (ushort_t*)alloc((size_t)NF * NH * 2);  // packed W1
    ushort_t* W2p      = (ushort_t*)alloc((size_t)NH * NH * 2);  // packed W2
    float*    bufC     = (float*)alloc((size_t)N * 4);           // H2·W3 [N] f32
    (void)ws_size; (void)n_in; (void)out_size;

    int nbN = (N + 255) / 256;           // 196
    int nbE = (E + 255) / 256;           // 2500

    // graph prep
    init_kernel<<<nbN, 256, 0, stream>>>(deg, fill, N);
    count_kernel<<<nbE, 256, 0, stream>>>(dst, deg, E);
    dis_kernel<<<nbN, 256, 0, stream>>>(deg, dis, N);
    scan1_kernel<<<nbN, 256, 0, stream>>>(deg, rowptr, bsums, N);
    scan2_kernel<<<1, 256, 0, stream>>>(bsums, boff, nbN);
    scan3_kernel<<<nbN, 256, 0, stream>>>(rowptr, boff, N, E);
    fill_kernel<<<nbE, 256, 0, stream>>>(src, dst, rowptr, fill, dis, csr_src, csr_norm, E);

    // dtype prep
    int n8 = N * NF / 8;
    x2b_kernel<<<(n8 + 255) / 256, 256, 0, stream>>>(x, Xb, n8);
    packW_kernel<<<(NF * NH + 255) / 256, 256, 0, stream>>>(W1, W1p, NF * NH);
    packW_kernel<<<(NH * NH + 255) / 256, 256, 0, stream>>>(W2, W2p, NH * NH);

    int nbA = (N + 3) / 4;               // 12500 (4 waves/block)
    int nbM = (N + 63) / 64;             // 782

    // layer 1: AXb = Â·Xb ; H1 = bf16(relu(AXb@W1 + b1))
    aggb_128_kernel<<<nbA, 256, 0, stream>>>(Xb, rowptr, csr_src, csr_norm, dis, bufAXb, N);
    mfma_gemm_kernel<NF, 1><<<nbM, 256, 0, stream>>>(bufAXb, W1p, b1, nullptr, nullptr, bufH1, N);
    // layer 2: Gb = Â·H1 ; C = relu(Gb@W2 + b2)·W3
    aggb_256_kernel<<<nbA, 256, 0, stream>>>(bufH1, rowptr, csr_src, csr_norm, dis, bufGb, N);
    mfma_gemm_kernel<NH, 2><<<nbM, 256, 0, stream>>>(bufGb, W2p, b2, W3, bufC, nullptr, N);
    // layer 3: out = sigmoid(Â·C + b3)
    agg1_kernel<<<nbN, 256, 0, stream>>>(bufC, rowptr, csr_src, csr_norm, dis, b3,
                                         (float*)d_out, N);
}

// Round 11
// 217.149 us; speedup vs baseline: 2.0190x; 1.3303x over previous
//
#include <hip/hip_runtime.h>
#include <math.h>

#define NF 128
#define NH 256

typedef unsigned short ushort_t;
typedef __attribute__((ext_vector_type(8))) short bf16x8;
typedef __attribute__((ext_vector_type(8))) unsigned short u16x8;
typedef __attribute__((ext_vector_type(4))) float f32x4;

__device__ __forceinline__ float b2f(ushort_t h) {
    return __uint_as_float((unsigned int)h << 16);
}
__device__ __forceinline__ ushort_t f2b(float f) {
    unsigned int u = __float_as_uint(f);
    unsigned int r = (u + 0x7FFF + ((u >> 16) & 1)) >> 16;   // RNE
    return (ushort_t)r;
}

// ---------------- graph prep ----------------

__global__ void init_kernel(int* __restrict__ deg, int* __restrict__ fill, int N) {
    int i = blockIdx.x * blockDim.x + threadIdx.x;
    if (i < N) { deg[i] = 1; fill[i] = 0; }   // 1 = self-loop
}

__global__ void count_kernel(const int* __restrict__ dst, int* __restrict__ deg, int E) {
    int i = blockIdx.x * blockDim.x + threadIdx.x;
    if (i < E) atomicAdd(&deg[dst[i]], 1);
}

__global__ void dis_kernel(const int* __restrict__ deg, float* __restrict__ dis, int N) {
    int i = blockIdx.x * blockDim.x + threadIdx.x;
    if (i < N) dis[i] = rsqrtf((float)deg[i]);
}

__global__ void scan1_kernel(const int* __restrict__ deg, int* __restrict__ rowptr,
                             int* __restrict__ bsums, int N) {
    __shared__ int sm[256];
    int i = blockIdx.x * 256 + threadIdx.x;
    int v = (i < N) ? (deg[i] - 1) : 0;
    sm[threadIdx.x] = v;
    __syncthreads();
    int s = v;
    for (int off = 1; off < 256; off <<= 1) {
        int t = 0;
        if ((int)threadIdx.x >= off) t = sm[threadIdx.x - off];
        __syncthreads();
        s += t;
        sm[threadIdx.x] = s;
        __syncthreads();
    }
    if (i < N) rowptr[i] = s - v;
    if (threadIdx.x == 255) bsums[blockIdx.x] = s;
}

__global__ void scan2_kernel(const int* __restrict__ bsums, int* __restrict__ boff, int NB) {
    __shared__ int sm[256];
    int t = threadIdx.x;
    int v = (t < NB) ? bsums[t] : 0;
    sm[t] = v;
    __syncthreads();
    int s = v;
    for (int off = 1; off < 256; off <<= 1) {
        int x = 0;
        if (t >= off) x = sm[t - off];
        __syncthreads();
        s += x;
        sm[t] = s;
        __syncthreads();
    }
    boff[t] = s - v;
}

__global__ void scan3_kernel(int* __restrict__ rowptr, const int* __restrict__ boff, int N, int E) {
    int i = blockIdx.x * 256 + threadIdx.x;
    if (i < N) rowptr[i] += boff[blockIdx.x];
    if (blockIdx.x == 0 && threadIdx.x == 0) rowptr[N] = E;
}

__global__ void fill_kernel(const int* __restrict__ src, const int* __restrict__ dst,
                            const int* __restrict__ rowptr, int* __restrict__ fill,
                            const float* __restrict__ dis,
                            int* __restrict__ csr_src, float* __restrict__ csr_norm, int E) {
    int i = blockIdx.x * blockDim.x + threadIdx.x;
    if (i >= E) return;
    int s = src[i], d = dst[i];
    int pos = atomicAdd(&fill[d], 1);
    int idx = rowptr[d] + pos;
    csr_src[idx] = s;
    csr_norm[idx] = dis[s] * dis[d];
}

// ---------------- dtype prep ----------------

__global__ void x2b_kernel(const float* __restrict__ X, ushort_t* __restrict__ Xb, int n8) {
    int i = blockIdx.x * 256 + threadIdx.x;
    if (i >= n8) return;
    const float4* X4 = reinterpret_cast<const float4*>(X);
    float4 a = X4[i * 2], b = X4[i * 2 + 1];
    ushort4 lo, hi;
    lo.x = f2b(a.x); lo.y = f2b(a.y); lo.z = f2b(a.z); lo.w = f2b(a.w);
    hi.x = f2b(b.x); hi.y = f2b(b.y); hi.z = f2b(b.z); hi.w = f2b(b.w);
    reinterpret_cast<ushort4*>(Xb)[i * 2]     = lo;
    reinterpret_cast<ushort4*>(Xb)[i * 2 + 1] = hi;
}

// Pack W [K][256] f32 into MFMA B-fragment layout: [K/32][16 ct][64 lane][8]
__global__ void packW_kernel(const float* __restrict__ W, ushort_t* __restrict__ Bp, int total) {
    int idx = blockIdx.x * 256 + threadIdx.x;
    if (idx >= total) return;
    int j    = idx & 7;
    int lane = (idx >> 3) & 63;
    int ct   = (idx >> 9) & 15;
    int kk   = idx >> 13;
    int k    = kk * 32 + (lane >> 4) * 8 + j;
    int col  = ct * 16 + (lane & 15);
    Bp[idx] = f2b(W[(size_t)k * 256 + col]);
}

// ------------- aggregation, bf16, 128 feats: 4 nodes/wave, 16 lanes x ushort8 per row -------------

__global__ __launch_bounds__(256) void aggb_128_kernel(const ushort_t* __restrict__ Xb,
                                                       const int* __restrict__ rowptr,
                                                       const int* __restrict__ csr_src,
                                                       const float* __restrict__ csr_norm,
                                                       const float* __restrict__ dis,
                                                       ushort_t* __restrict__ Out, int N) {
    int sub  = threadIdx.x & 15;                     // lane within row
    int node = blockIdx.x * 16 + (threadIdx.x >> 4); // 16 nodes per 256-thread block
    bool valid = node < N;
    int nd = valid ? node : N - 1;

    const u16x8* X8 = reinterpret_cast<const u16x8*>(Xb);   // row stride = 16
    float dn = dis[nd];
    float n0 = dn * dn;
    u16x8 sv = X8[(size_t)nd * 16 + sub];
    float acc[8];
#pragma unroll
    for (int t = 0; t < 8; ++t) acc[t] = b2f(sv[t]) * n0;

    int j = rowptr[nd], end = rowptr[nd + 1];
    for (; j + 4 <= end; j += 4) {
        int s0 = csr_src[j],     s1 = csr_src[j + 1];
        int s2 = csr_src[j + 2], s3 = csr_src[j + 3];
        float m0 = csr_norm[j],     m1 = csr_norm[j + 1];
        float m2 = csr_norm[j + 2], m3 = csr_norm[j + 3];
        u16x8 v0 = X8[(size_t)s0 * 16 + sub];
        u16x8 v1 = X8[(size_t)s1 * 16 + sub];
        u16x8 v2 = X8[(size_t)s2 * 16 + sub];
        u16x8 v3 = X8[(size_t)s3 * 16 + sub];
#pragma unroll
        for (int t = 0; t < 8; ++t) {
            acc[t] = fmaf(b2f(v0[t]), m0, acc[t]);
            acc[t] = fmaf(b2f(v1[t]), m1, acc[t]);
            acc[t] = fmaf(b2f(v2[t]), m2, acc[t]);
            acc[t] = fmaf(b2f(v3[t]), m3, acc[t]);
        }
    }
    for (; j < end; ++j) {
        int s = csr_src[j];
        float m = csr_norm[j];
        u16x8 v = X8[(size_t)s * 16 + sub];
#pragma unroll
        for (int t = 0; t < 8; ++t) acc[t] = fmaf(b2f(v[t]), m, acc[t]);
    }
    if (valid) {
        u16x8 o;
#pragma unroll
        for (int t = 0; t < 8; ++t) o[t] = f2b(acc[t]);
        reinterpret_cast<u16x8*>(Out)[(size_t)node * 16 + sub] = o;
    }
}

// ------------- aggregation, bf16, 256 feats: 2 nodes/wave, 32 lanes x ushort8 per row -------------

__global__ __launch_bounds__(256) void aggb_256_kernel(const ushort_t* __restrict__ H,
                                                       const int* __restrict__ rowptr,
                                                       const int* __restrict__ csr_src,
                                                       const float* __restrict__ csr_norm,
                                                       const float* __restrict__ dis,
                                                       ushort_t* __restrict__ Out, int N) {
    int sub  = threadIdx.x & 31;                     // lane within row
    int node = blockIdx.x * 8 + (threadIdx.x >> 5);  // 8 nodes per 256-thread block
    bool valid = node < N;
    int nd = valid ? node : N - 1;

    const u16x8* H8 = reinterpret_cast<const u16x8*>(H);    // row stride = 32
    float dn = dis[nd];
    float n0 = dn * dn;
    u16x8 sv = H8[(size_t)nd * 32 + sub];
    float acc[8];
#pragma unroll
    for (int t = 0; t < 8; ++t) acc[t] = b2f(sv[t]) * n0;

    int j = rowptr[nd], end = rowptr[nd + 1];
    for (; j + 4 <= end; j += 4) {
        int s0 = csr_src[j],     s1 = csr_src[j + 1];
        int s2 = csr_src[j + 2], s3 = csr_src[j + 3];
        float m0 = csr_norm[j],     m1 = csr_norm[j + 1];
        float m2 = csr_norm[j + 2], m3 = csr_norm[j + 3];
        u16x8 v0 = H8[(size_t)s0 * 32 + sub];
        u16x8 v1 = H8[(size_t)s1 * 32 + sub];
        u16x8 v2 = H8[(size_t)s2 * 32 + sub];
        u16x8 v3 = H8[(size_t)s3 * 32 + sub];
#pragma unroll
        for (int t = 0; t < 8; ++t) {
            acc[t] = fmaf(b2f(v0[t]), m0, acc[t]);
            acc[t] = fmaf(b2f(v1[t]), m1, acc[t]);
            acc[t] = fmaf(b2f(v2[t]), m2, acc[t]);
            acc[t] = fmaf(b2f(v3[t]), m3, acc[t]);
        }
    }
    for (; j < end; ++j) {
        int s = csr_src[j];
        float m = csr_norm[j];
        u16x8 v = H8[(size_t)s * 32 + sub];
#pragma unroll
        for (int t = 0; t < 8; ++t) acc[t] = fmaf(b2f(v[t]), m, acc[t]);
    }
    if (valid) {
        u16x8 o;
#pragma unroll
        for (int t = 0; t < 8; ++t) o[t] = f2b(acc[t]);
        reinterpret_cast<u16x8*>(Out)[(size_t)node * 32 + sub] = o;
    }
}

// ---------------- MFMA GEMM: A[N,K] bf16 @ Wp (packed) -> 256 cols ----------------

template <int K, int MODE>
__global__ __launch_bounds__(256) void mfma_gemm_kernel(const ushort_t* __restrict__ A,
                                                        const ushort_t* __restrict__ Bp,
                                                        const float* __restrict__ bias,
                                                        const float* __restrict__ W3,
                                                        float* __restrict__ OutF,
                                                        ushort_t* __restrict__ OutB, int N) {
    int wid  = threadIdx.x >> 6;
    int lane = threadIdx.x & 63;
    int row0 = blockIdx.x * 64 + wid * 16;

    int ar = row0 + (lane & 15);
    if (ar >= N) ar = N - 1;                 // clamp; stores are guarded below
    const ushort_t* arow = A + (size_t)ar * K + (lane >> 4) * 8;

    f32x4 acc[16];
#pragma unroll
    for (int ct = 0; ct < 16; ++ct) acc[ct] = (f32x4){0.f, 0.f, 0.f, 0.f};

    const bf16x8* Bv = reinterpret_cast<const bf16x8*>(Bp);
#pragma unroll
    for (int kk = 0; kk < K / 32; ++kk) {
        bf16x8 a = *reinterpret_cast<const bf16x8*>(arow + kk * 32);
        const bf16x8* bbase = Bv + (size_t)kk * 1024 + lane;
#pragma unroll
        for (int ct = 0; ct < 16; ++ct) {
            bf16x8 b = bbase[ct * 64];
            acc[ct] = __builtin_amdgcn_mfma_f32_16x16x32_bf16(a, b, acc[ct], 0, 0, 0);
        }
    }

    int orow = row0 + (lane >> 4) * 4;
    int ocol = lane & 15;

    if (MODE == 1) {
#pragma unroll
        for (int r = 0; r < 4; ++r) {
            int gr = orow + r;
            if (gr < N) {
#pragma unroll
                for (int ct = 0; ct < 16; ++ct) {
                    float v = fmaxf(acc[ct][r] + bias[ct * 16 + ocol], 0.f);
                    OutB[(size_t)gr * 256 + ct * 16 + ocol] = f2b(v);
                }
            }
        }
    } else {
#pragma unroll
        for (int r = 0; r < 4; ++r) {
            float p = 0.f;
#pragma unroll
            for (int ct = 0; ct < 16; ++ct) {
                float v = fmaxf(acc[ct][r] + bias[ct * 16 + ocol], 0.f);
                p = fmaf(v, W3[ct * 16 + ocol], p);
            }
            p += __shfl_xor(p, 1);
            p += __shfl_xor(p, 2);
            p += __shfl_xor(p, 4);
            p += __shfl_xor(p, 8);
            int gr = orow + r;
            if (ocol == 0 && gr < N) OutF[gr] = p;
        }
    }
}

// ------------- final 1-wide aggregation + sigmoid (unrolled) -------------

__global__ void agg1_kernel(const float* __restrict__ c, const int* __restrict__ rowptr,
                            const int* __restrict__ csr_src, const float* __restrict__ csr_norm,
                            const float* __restrict__ dis, const float* __restrict__ b3,
                            float* __restrict__ out, int N) {
    int i = blockIdx.x * blockDim.x + threadIdx.x;
    if (i >= N) return;
    float dn = dis[i];
    float acc = c[i] * dn * dn;
    int j = rowptr[i], end = rowptr[i + 1];
    for (; j + 4 <= end; j += 4) {
        float c0 = c[csr_src[j]],     c1 = c[csr_src[j + 1]];
        float c2 = c[csr_src[j + 2]], c3 = c[csr_src[j + 3]];
        acc = fmaf(c0, csr_norm[j], acc);
        acc = fmaf(c1, csr_norm[j + 1], acc);
        acc = fmaf(c2, csr_norm[j + 2], acc);
        acc = fmaf(c3, csr_norm[j + 3], acc);
    }
    for (; j < end; ++j) acc += c[csr_src[j]] * csr_norm[j];
    acc += b3[0];
    out[i] = 1.0f / (1.0f + expf(-acc));
}

// ---------------- launch ----------------

extern "C" void kernel_launch(void* const* d_in, const int* in_sizes, int n_in,
                              void* d_out, int out_size, void* d_ws, size_t ws_size,
                              hipStream_t stream) {
    const float* x  = (const float*)d_in[0];
    const int*   ei = (const int*)d_in[1];
    const float* W1 = (const float*)d_in[2];
    const float* b1 = (const float*)d_in[3];
    const float* W2 = (const float*)d_in[4];
    const float* b2 = (const float*)d_in[5];
    const float* W3 = (const float*)d_in[6];
    const float* b3 = (const float*)d_in[7];

    int N = in_sizes[0] / NF;      // 50000
    int E = in_sizes[1] / 2;       // 640000
    const int* src = ei;
    const int* dst = ei + E;

    char* ws = (char*)d_ws;
    auto alloc = [&](size_t bytes) -> void* {
        void* p = (void*)ws;
        ws += (bytes + 255) & ~(size_t)255;
        return p;
    };
    int*      deg      = (int*)alloc((size_t)N * 4);
    int*      fill     = (int*)alloc((size_t)N * 4);
    float*    dis      = (float*)alloc((size_t)N * 4);
    int*      rowptr   = (int*)alloc((size_t)(N + 1) * 4);
    int*      bsums    = (int*)alloc(1024);
    int*      boff     = (int*)alloc(1024);
    int*      csr_src  = (int*)alloc((size_t)E * 4);
    float*    csr_norm = (float*)alloc((size_t)E * 4);
    ushort_t* Xb       = (ushort_t*)alloc((size_t)N * NF * 2);   // X bf16        [N,128]
    ushort_t* bufAXb   = (ushort_t*)alloc((size_t)N * NF * 2);   // Â·X bf16      [N,128]
    ushort_t* bufH1    = (ushort_t*)alloc((size_t)N * NH * 2);   // H1 bf16       [N,256]
    ushort_t* bufGb    = (ushort_t*)alloc((size_t)N * NH * 2);   // Â·H1 bf16     [N,256]
    ushort_t* W1p      = (ushort_t*)alloc((size_t)NF * NH * 2);  // packed W1
    ushort_t* W2p      = (ushort_t*)alloc((size_t)NH * NH * 2);  // packed W2
    float*    bufC     = (float*)alloc((size_t)N * 4);           // H2·W3 [N] f32
    (void)ws_size; (void)n_in; (void)out_size;

    int nbN = (N + 255) / 256;           // 196
    int nbE = (E + 255) / 256;           // 2500

    // graph prep
    init_kernel<<<nbN, 256, 0, stream>>>(deg, fill, N);
    count_kernel<<<nbE, 256, 0, stream>>>(dst, deg, E);
    dis_kernel<<<nbN, 256, 0, stream>>>(deg, dis, N);
    scan1_kernel<<<nbN, 256, 0, stream>>>(deg, rowptr, bsums, N);
    scan2_kernel<<<1, 256, 0, stream>>>(bsums, boff, nbN);
    scan3_kernel<<<nbN, 256, 0, stream>>>(rowptr, boff, N, E);
    fill_kernel<<<nbE, 256, 0, stream>>>(src, dst, rowptr, fill, dis, csr_src, csr_norm, E);

    // dtype prep
    int n8 = N * NF / 8;
    x2b_kernel<<<(n8 + 255) / 256, 256, 0, stream>>>(x, Xb, n8);
    packW_kernel<<<(NF * NH + 255) / 256, 256, 0, stream>>>(W1, W1p, NF * NH);
    packW_kernel<<<(NH * NH + 255) / 256, 256, 0, stream>>>(W2, W2p, NH * NH);

    int nbA128 = (N + 15) / 16;          // 3125 (16 nodes/block)
    int nbA256 = (N + 7) / 8;            // 6250 (8 nodes/block)
    int nbM = (N + 63) / 64;             // 782

    // layer 1: AXb = Â·Xb ; H1 = bf16(relu(AXb@W1 + b1))
    aggb_128_kernel<<<nbA128, 256, 0, stream>>>(Xb, rowptr, csr_src, csr_norm, dis, bufAXb, N);
    mfma_gemm_kernel<NF, 1><<<nbM, 256, 0, stream>>>(bufAXb, W1p, b1, nullptr, nullptr, bufH1, N);
    // layer 2: Gb = Â·H1 ; C = relu(Gb@W2 + b2)·W3
    aggb_256_kernel<<<nbA256, 256, 0, stream>>>(bufH1, rowptr, csr_src, csr_norm, dis, bufGb, N);
    mfma_gemm_kernel<NH, 2><<<nbM, 256, 0, stream>>>(bufGb, W2p, b2, W3, bufC, nullptr, N);
    // layer 3: out = sigmoid(Â·C + b3)
    agg1_kernel<<<nbN, 256, 0, stream>>>(bufC, rowptr, csr_src, csr_norm, dis, b3,
                                         (float*)d_out, N);
}

// Round 13
// 200.838 us; speedup vs baseline: 2.1830x; 1.0812x over previous
//
#include <hip/hip_runtime.h>
#include <math.h>

#define NF 128
#define NH 256

typedef unsigned short ushort_t;
typedef unsigned char uchar_t;
typedef unsigned int uint_t;
typedef __attribute__((ext_vector_type(8))) short bf16x8;
typedef __attribute__((ext_vector_type(8))) unsigned short u16x8;
typedef __attribute__((ext_vector_type(4))) float f32x4;
typedef __attribute__((ext_vector_type(2))) float f32x2;

__device__ __forceinline__ float b2f(ushort_t h) {
    return __uint_as_float((unsigned int)h << 16);
}
__device__ __forceinline__ ushort_t f2b(float f) {
    unsigned int u = __float_as_uint(f);
    unsigned int r = (u + 0x7FFF + ((u >> 16) & 1)) >> 16;   // RNE
    return (ushort_t)r;
}
// f32 -> OCP fp8 e4m3 (RNE, saturating) via HW cvt
__device__ __forceinline__ uchar_t f2fp8(float f) {
    int p = __builtin_amdgcn_cvt_pk_fp8_f32(f, f, 0, false);
    return (uchar_t)(p & 0xFF);
}

// ---------------- graph prep ----------------

__global__ void init_kernel(int* __restrict__ deg, int* __restrict__ fill, int N) {
    int i = blockIdx.x * blockDim.x + threadIdx.x;
    if (i < N) { deg[i] = 1; fill[i] = 0; }   // 1 = self-loop
}

__global__ void count_kernel(const int* __restrict__ dst, int* __restrict__ deg, int E) {
    int i = blockIdx.x * blockDim.x + threadIdx.x;
    if (i < E) atomicAdd(&deg[dst[i]], 1);
}

__global__ void dis_kernel(const int* __restrict__ deg, float* __restrict__ dis, int N) {
    int i = blockIdx.x * blockDim.x + threadIdx.x;
    if (i < N) dis[i] = rsqrtf((float)deg[i]);
}

__global__ void scan1_kernel(const int* __restrict__ deg, int* __restrict__ rowptr,
                             int* __restrict__ bsums, int N) {
    __shared__ int sm[256];
    int i = blockIdx.x * 256 + threadIdx.x;
    int v = (i < N) ? (deg[i] - 1) : 0;
    sm[threadIdx.x] = v;
    __syncthreads();
    int s = v;
    for (int off = 1; off < 256; off <<= 1) {
        int t = 0;
        if ((int)threadIdx.x >= off) t = sm[threadIdx.x - off];
        __syncthreads();
        s += t;
        sm[threadIdx.x] = s;
        __syncthreads();
    }
    if (i < N) rowptr[i] = s - v;
    if (threadIdx.x == 255) bsums[blockIdx.x] = s;
}

__global__ void scan2_kernel(const int* __restrict__ bsums, int* __restrict__ boff, int NB) {
    __shared__ int sm[256];
    int t = threadIdx.x;
    int v = (t < NB) ? bsums[t] : 0;
    sm[t] = v;
    __syncthreads();
    int s = v;
    for (int off = 1; off < 256; off <<= 1) {
        int x = 0;
        if (t >= off) x = sm[t - off];
        __syncthreads();
        s += x;
        sm[t] = s;
        __syncthreads();
    }
    boff[t] = s - v;
}

__global__ void scan3_kernel(int* __restrict__ rowptr, const int* __restrict__ boff, int N, int E) {
    int i = blockIdx.x * 256 + threadIdx.x;
    if (i < N) rowptr[i] += boff[blockIdx.x];
    if (blockIdx.x == 0 && threadIdx.x == 0) rowptr[N] = E;
}

__global__ void fill_kernel(const int* __restrict__ src, const int* __restrict__ dst,
                            const int* __restrict__ rowptr, int* __restrict__ fill,
                            const float* __restrict__ dis,
                            int* __restrict__ csr_src, float* __restrict__ csr_norm, int E) {
    int i = blockIdx.x * blockDim.x + threadIdx.x;
    if (i >= E) return;
    int s = src[i], d = dst[i];
    int pos = atomicAdd(&fill[d], 1);
    int idx = rowptr[d] + pos;
    csr_src[idx] = s;
    csr_norm[idx] = dis[s] * dis[d];
}

// ---------------- dtype prep ----------------

__global__ void x2b_kernel(const float* __restrict__ X, ushort_t* __restrict__ Xb, int n8) {
    int i = blockIdx.x * 256 + threadIdx.x;
    if (i >= n8) return;
    const float4* X4 = reinterpret_cast<const float4*>(X);
    float4 a = X4[i * 2], b = X4[i * 2 + 1];
    ushort4 lo, hi;
    lo.x = f2b(a.x); lo.y = f2b(a.y); lo.z = f2b(a.z); lo.w = f2b(a.w);
    hi.x = f2b(b.x); hi.y = f2b(b.y); hi.z = f2b(b.z); hi.w = f2b(b.w);
    reinterpret_cast<ushort4*>(Xb)[i * 2]     = lo;
    reinterpret_cast<ushort4*>(Xb)[i * 2 + 1] = hi;
}

// Pack W [K][256] f32 into MFMA B-fragment layout: [K/32][16 ct][64 lane][8]
__global__ void packW_kernel(const float* __restrict__ W, ushort_t* __restrict__ Bp, int total) {
    int idx = blockIdx.x * 256 + threadIdx.x;
    if (idx >= total) return;
    int j    = idx & 7;
    int lane = (idx >> 3) & 63;
    int ct   = (idx >> 9) & 15;
    int kk   = idx >> 13;
    int k    = kk * 32 + (lane >> 4) * 8 + j;
    int col  = ct * 16 + (lane & 15);
    Bp[idx] = f2b(W[(size_t)k * 256 + col]);
}

// ------------- aggregation, bf16, 128 feats: 4 nodes/wave, 16 lanes x ushort8 per row -------------

__global__ __launch_bounds__(256) void aggb_128_kernel(const ushort_t* __restrict__ Xb,
                                                       const int* __restrict__ rowptr,
                                                       const int* __restrict__ csr_src,
                                                       const float* __restrict__ csr_norm,
                                                       const float* __restrict__ dis,
                                                       ushort_t* __restrict__ Out, int N) {
    int sub  = threadIdx.x & 15;
    int node = blockIdx.x * 16 + (threadIdx.x >> 4);
    bool valid = node < N;
    int nd = valid ? node : N - 1;

    const u16x8* X8 = reinterpret_cast<const u16x8*>(Xb);   // row stride = 16
    float dn = dis[nd];
    float n0 = dn * dn;
    u16x8 sv = X8[(size_t)nd * 16 + sub];
    float acc[8];
#pragma unroll
    for (int t = 0; t < 8; ++t) acc[t] = b2f(sv[t]) * n0;

    int j = rowptr[nd], end = rowptr[nd + 1];
    for (; j + 4 <= end; j += 4) {
        int s0 = csr_src[j],     s1 = csr_src[j + 1];
        int s2 = csr_src[j + 2], s3 = csr_src[j + 3];
        float m0 = csr_norm[j],     m1 = csr_norm[j + 1];
        float m2 = csr_norm[j + 2], m3 = csr_norm[j + 3];
        u16x8 v0 = X8[(size_t)s0 * 16 + sub];
        u16x8 v1 = X8[(size_t)s1 * 16 + sub];
        u16x8 v2 = X8[(size_t)s2 * 16 + sub];
        u16x8 v3 = X8[(size_t)s3 * 16 + sub];
#pragma unroll
        for (int t = 0; t < 8; ++t) {
            acc[t] = fmaf(b2f(v0[t]), m0, acc[t]);
            acc[t] = fmaf(b2f(v1[t]), m1, acc[t]);
            acc[t] = fmaf(b2f(v2[t]), m2, acc[t]);
            acc[t] = fmaf(b2f(v3[t]), m3, acc[t]);
        }
    }
    for (; j < end; ++j) {
        int s = csr_src[j];
        float m = csr_norm[j];
        u16x8 v = X8[(size_t)s * 16 + sub];
#pragma unroll
        for (int t = 0; t < 8; ++t) acc[t] = fmaf(b2f(v[t]), m, acc[t]);
    }
    if (valid) {
        u16x8 o;
#pragma unroll
        for (int t = 0; t < 8; ++t) o[t] = f2b(acc[t]);
        reinterpret_cast<u16x8*>(Out)[(size_t)node * 16 + sub] = o;
    }
}

// ------------- aggregation over fp8 H1 table, 256 feats: wave/node, lane owns 4 fp8 -------------
// G[n] (bf16 out) = sum_e fp8dec(H1[src_e]) * norm_e + fp8dec(H1[n]) * dis[n]^2

#define ACC4(w, m)                                                          \
    {                                                                       \
        f32x2 lo_ = __builtin_amdgcn_cvt_pk_f32_fp8((int)(w), false);       \
        f32x2 hi_ = __builtin_amdgcn_cvt_pk_f32_fp8((int)(w), true);        \
        a0 = fmaf(lo_[0], (m), a0); a1 = fmaf(lo_[1], (m), a1);             \
        a2 = fmaf(hi_[0], (m), a2); a3 = fmaf(hi_[1], (m), a3);             \
    }

__global__ __launch_bounds__(256) void aggf8_256_kernel(const uchar_t* __restrict__ H8,
                                                        const int* __restrict__ rowptr,
                                                        const int* __restrict__ csr_src,
                                                        const float* __restrict__ csr_norm,
                                                        const float* __restrict__ dis,
                                                        ushort_t* __restrict__ Out, int N) {
    int lane = threadIdx.x & 63;
    int node = blockIdx.x * (blockDim.x >> 6) + (threadIdx.x >> 6);
    if (node >= N) return;

    const uint_t* T = reinterpret_cast<const uint_t*>(H8);   // row = 64 dwords (256 fp8)
    float dn = dis[node];
    float n0 = dn * dn;
    float a0, a1, a2, a3;
    {
        uint_t w = T[(size_t)node * 64 + lane];
        f32x2 lo_ = __builtin_amdgcn_cvt_pk_f32_fp8((int)w, false);
        f32x2 hi_ = __builtin_amdgcn_cvt_pk_f32_fp8((int)w, true);
        a0 = lo_[0] * n0; a1 = lo_[1] * n0; a2 = hi_[0] * n0; a3 = hi_[1] * n0;
    }

    int j = rowptr[node], end = rowptr[node + 1];
    for (; j + 8 <= end; j += 8) {
        int s0 = csr_src[j],     s1 = csr_src[j + 1];
        int s2 = csr_src[j + 2], s3 = csr_src[j + 3];
        int s4 = csr_src[j + 4], s5 = csr_src[j + 5];
        int s6 = csr_src[j + 6], s7 = csr_src[j + 7];
        float m0 = csr_norm[j],     m1 = csr_norm[j + 1];
        float m2 = csr_norm[j + 2], m3 = csr_norm[j + 3];
        float m4 = csr_norm[j + 4], m5 = csr_norm[j + 5];
        float m6 = csr_norm[j + 6], m7 = csr_norm[j + 7];
        uint_t w0 = T[(size_t)s0 * 64 + lane];
        uint_t w1 = T[(size_t)s1 * 64 + lane];
        uint_t w2 = T[(size_t)s2 * 64 + lane];
        uint_t w3 = T[(size_t)s3 * 64 + lane];
        uint_t w4 = T[(size_t)s4 * 64 + lane];
        uint_t w5 = T[(size_t)s5 * 64 + lane];
        uint_t w6 = T[(size_t)s6 * 64 + lane];
        uint_t w7 = T[(size_t)s7 * 64 + lane];
        ACC4(w0, m0) ACC4(w1, m1) ACC4(w2, m2) ACC4(w3, m3)
        ACC4(w4, m4) ACC4(w5, m5) ACC4(w6, m6) ACC4(w7, m7)
    }
    for (; j + 4 <= end; j += 4) {
        int s0 = csr_src[j],     s1 = csr_src[j + 1];
        int s2 = csr_src[j + 2], s3 = csr_src[j + 3];
        float m0 = csr_norm[j],     m1 = csr_norm[j + 1];
        float m2 = csr_norm[j + 2], m3 = csr_norm[j + 3];
        uint_t w0 = T[(size_t)s0 * 64 + lane];
        uint_t w1 = T[(size_t)s1 * 64 + lane];
        uint_t w2 = T[(size_t)s2 * 64 + lane];
        uint_t w3 = T[(size_t)s3 * 64 + lane];
        ACC4(w0, m0) ACC4(w1, m1) ACC4(w2, m2) ACC4(w3, m3)
    }
    for (; j < end; ++j) {
        int s = csr_src[j];
        float m = csr_norm[j];
        uint_t w = T[(size_t)s * 64 + lane];
        ACC4(w, m)
    }

    ushort4 o;
    o.x = f2b(a0); o.y = f2b(a1); o.z = f2b(a2); o.w = f2b(a3);
    reinterpret_cast<ushort4*>(Out)[(size_t)node * 64 + lane] = o;   // bf16 [N,256]
}

// ---------------- MFMA GEMM: A[N,K] bf16 @ Wp (packed) -> 256 cols ----------------
// MODE 1: OutB8 = fp8e4m3(relu(acc + bias))  [N,256] row-major (gather table)
// MODE 2: OutF  = relu(acc + bias) . W3      [N] f32

template <int K, int MODE>
__global__ __launch_bounds__(256) void mfma_gemm_kernel(const ushort_t* __restrict__ A,
                                                        const ushort_t* __restrict__ Bp,
                                                        const float* __restrict__ bias,
                                                        const float* __restrict__ W3,
                                                        float* __restrict__ OutF,
                                                        uchar_t* __restrict__ OutB8, int N) {
    int wid  = threadIdx.x >> 6;
    int lane = threadIdx.x & 63;
    int row0 = blockIdx.x * 64 + wid * 16;

    int ar = row0 + (lane & 15);
    if (ar >= N) ar = N - 1;                 // clamp; stores are guarded below
    const ushort_t* arow = A + (size_t)ar * K + (lane >> 4) * 8;

    f32x4 acc[16];
#pragma unroll
    for (int ct = 0; ct < 16; ++ct) acc[ct] = (f32x4){0.f, 0.f, 0.f, 0.f};

    const bf16x8* Bv = reinterpret_cast<const bf16x8*>(Bp);
#pragma unroll
    for (int kk = 0; kk < K / 32; ++kk) {
        bf16x8 a = *reinterpret_cast<const bf16x8*>(arow + kk * 32);
        const bf16x8* bbase = Bv + (size_t)kk * 1024 + lane;
#pragma unroll
        for (int ct = 0; ct < 16; ++ct) {
            bf16x8 b = bbase[ct * 64];
            acc[ct] = __builtin_amdgcn_mfma_f32_16x16x32_bf16(a, b, acc[ct], 0, 0, 0);
        }
    }

    int orow = row0 + (lane >> 4) * 4;
    int ocol = lane & 15;

    if (MODE == 1) {
#pragma unroll
        for (int r = 0; r < 4; ++r) {
            int gr = orow + r;
            if (gr < N) {
#pragma unroll
                for (int ct = 0; ct < 16; ++ct) {
                    float v = fmaxf(acc[ct][r] + bias[ct * 16 + ocol], 0.f);
                    OutB8[(size_t)gr * 256 + ct * 16 + ocol] = f2fp8(v);
                }
            }
        }
    } else {
#pragma unroll
        for (int r = 0; r < 4; ++r) {
            float p = 0.f;
#pragma unroll
            for (int ct = 0; ct < 16; ++ct) {
                float v = fmaxf(acc[ct][r] + bias[ct * 16 + ocol], 0.f);
                p = fmaf(v, W3[ct * 16 + ocol], p);
            }
            p += __shfl_xor(p, 1);
            p += __shfl_xor(p, 2);
            p += __shfl_xor(p, 4);
            p += __shfl_xor(p, 8);
            int gr = orow + r;
            if (ocol == 0 && gr < N) OutF[gr] = p;
        }
    }
}

// ------------- final 1-wide aggregation + sigmoid (unrolled) -------------

__global__ void agg1_kernel(const float* __restrict__ c, const int* __restrict__ rowptr,
                            const int* __restrict__ csr_src, const float* __restrict__ csr_norm,
                            const float* __restrict__ dis, const float* __restrict__ b3,
                            float* __restrict__ out, int N) {
    int i = blockIdx.x * blockDim.x + threadIdx.x;
    if (i >= N) return;
    float dn = dis[i];
    float acc = c[i] * dn * dn;
    int j = rowptr[i], end = rowptr[i + 1];
    for (; j + 4 <= end; j += 4) {
        float c0 = c[csr_src[j]],     c1 = c[csr_src[j + 1]];
        float c2 = c[csr_src[j + 2]], c3 = c[csr_src[j + 3]];
        acc = fmaf(c0, csr_norm[j], acc);
        acc = fmaf(c1, csr_norm[j + 1], acc);
        acc = fmaf(c2, csr_norm[j + 2], acc);
        acc = fmaf(c3, csr_norm[j + 3], acc);
    }
    for (; j < end; ++j) acc += c[csr_src[j]] * csr_norm[j];
    acc += b3[0];
    out[i] = 1.0f / (1.0f + expf(-acc));
}

// ---------------- launch ----------------

extern "C" void kernel_launch(void* const* d_in, const int* in_sizes, int n_in,
                              void* d_out, int out_size, void* d_ws, size_t ws_size,
                              hipStream_t stream) {
    const float* x  = (const float*)d_in[0];
    const int*   ei = (const int*)d_in[1];
    const float* W1 = (const float*)d_in[2];
    const float* b1 = (const float*)d_in[3];
    const float* W2 = (const float*)d_in[4];
    const float* b2 = (const float*)d_in[5];
    const float* W3 = (const float*)d_in[6];
    const float* b3 = (const float*)d_in[7];

    int N = in_sizes[0] / NF;      // 50000
    int E = in_sizes[1] / 2;       // 640000
    const int* src = ei;
    const int* dst = ei + E;

    char* ws = (char*)d_ws;
    auto alloc = [&](size_t bytes) -> void* {
        void* p = (void*)ws;
        ws += (bytes + 255) & ~(size_t)255;
        return p;
    };
    int*      deg      = (int*)alloc((size_t)N * 4);
    int*      fill     = (int*)alloc((size_t)N * 4);
    float*    dis      = (float*)alloc((size_t)N * 4);
    int*      rowptr   = (int*)alloc((size_t)(N + 1) * 4);
    int*      bsums    = (int*)alloc(1024);
    int*      boff     = (int*)alloc(1024);
    int*      csr_src  = (int*)alloc((size_t)E * 4);
    float*    csr_norm = (float*)alloc((size_t)E * 4);
    ushort_t* Xb       = (ushort_t*)alloc((size_t)N * NF * 2);   // X bf16         [N,128]
    ushort_t* bufAXb   = (ushort_t*)alloc((size_t)N * NF * 2);   // Â·X bf16       [N,128]
    uchar_t*  bufH1    = (uchar_t*)alloc((size_t)N * NH);        // H1 fp8 e4m3    [N,256]
    ushort_t* bufGb    = (ushort_t*)alloc((size_t)N * NH * 2);   // Â·H1 bf16      [N,256]
    ushort_t* W1p      = (ushort_t*)alloc((size_t)NF * NH * 2);  // packed W1
    ushort_t* W2p      = (ushort_t*)alloc((size_t)NH * NH * 2);  // packed W2
    float*    bufC     = (float*)alloc((size_t)N * 4);           // H2·W3 [N] f32
    (void)ws_size; (void)n_in; (void)out_size;

    int nbN = (N + 255) / 256;           // 196
    int nbE = (E + 255) / 256;           // 2500

    // graph prep
    init_kernel<<<nbN, 256, 0, stream>>>(deg, fill, N);
    count_kernel<<<nbE, 256, 0, stream>>>(dst, deg, E);
    dis_kernel<<<nbN, 256, 0, stream>>>(deg, dis, N);
    scan1_kernel<<<nbN, 256, 0, stream>>>(deg, rowptr, bsums, N);
    scan2_kernel<<<1, 256, 0, stream>>>(bsums, boff, nbN);
    scan3_kernel<<<nbN, 256, 0, stream>>>(rowptr, boff, N, E);
    fill_kernel<<<nbE, 256, 0, stream>>>(src, dst, rowptr, fill, dis, csr_src, csr_norm, E);

    // dtype prep
    int n8 = N * NF / 8;
    x2b_kernel<<<(n8 + 255) / 256, 256, 0, stream>>>(x, Xb, n8);
    packW_kernel<<<(NF * NH + 255) / 256, 256, 0, stream>>>(W1, W1p, NF * NH);
    packW_kernel<<<(NH * NH + 255) / 256, 256, 0, stream>>>(W2, W2p, NH * NH);

    int nbA128 = (N + 15) / 16;          // 3125 (16 nodes/block)
    int nbA256 = (N + 3) / 4;            // 12500 (wave per node, 4/block)
    int nbM = (N + 63) / 64;             // 782

    // layer 1: AXb = Â·Xb ; H1(fp8) = fp8(relu(AXb@W1 + b1))
    aggb_128_kernel<<<nbA128, 256, 0, stream>>>(Xb, rowptr, csr_src, csr_norm, dis, bufAXb, N);
    mfma_gemm_kernel<NF, 1><<<nbM, 256, 0, stream>>>(bufAXb, W1p, b1, nullptr, nullptr, bufH1, N);
    // layer 2: Gb(bf16) = Â·H1(fp8) ; C = relu(Gb@W2 + b2)·W3
    aggf8_256_kernel<<<nbA256, 256, 0, stream>>>(bufH1, rowptr, csr_src, csr_norm, dis, bufGb, N);
    mfma_gemm_kernel<NH, 2><<<nbM, 256, 0, stream>>>(bufGb, W2p, b2, W3, bufC, nullptr, N);
    // layer 3: out = sigmoid(Â·C + b3)
    agg1_kernel<<<nbN, 256, 0, stream>>>(bufC, rowptr, csr_src, csr_norm, dis, b3,
                                         (float*)d_out, N);
}

// Round 14
// 194.926 us; speedup vs baseline: 2.2492x; 1.0303x over previous
//
#include <hip/hip_runtime.h>
#include <math.h>

#define NF 128
#define NH 256

typedef unsigned short ushort_t;
typedef unsigned char uchar_t;
typedef unsigned int uint_t;
typedef __attribute__((ext_vector_type(8))) short bf16x8;
typedef __attribute__((ext_vector_type(8))) unsigned short u16x8;
typedef __attribute__((ext_vector_type(4))) float f32x4;
typedef __attribute__((ext_vector_type(2))) float f32x2;

__device__ __forceinline__ float b2f(ushort_t h) {
    return __uint_as_float((unsigned int)h << 16);
}
__device__ __forceinline__ ushort_t f2b(float f) {
    unsigned int u = __float_as_uint(f);
    unsigned int r = (u + 0x7FFF + ((u >> 16) & 1)) >> 16;   // RNE
    return (ushort_t)r;
}
// f32 -> OCP fp8 e4m3 (RNE, saturating) via HW cvt
__device__ __forceinline__ uchar_t f2fp8(float f) {
    int p = __builtin_amdgcn_cvt_pk_fp8_f32(f, f, 0, false);
    return (uchar_t)(p & 0xFF);
}

// ---------------- graph prep ----------------

__global__ void init_kernel(int* __restrict__ deg, int* __restrict__ fill, int N) {
    int i = blockIdx.x * blockDim.x + threadIdx.x;
    if (i < N) { deg[i] = 1; fill[i] = 0; }   // 1 = self-loop
}

__global__ void count_kernel(const int* __restrict__ dst, int* __restrict__ deg, int E) {
    int i = blockIdx.x * blockDim.x + threadIdx.x;
    if (i < E) atomicAdd(&deg[dst[i]], 1);
}

__global__ void dis_kernel(const int* __restrict__ deg, float* __restrict__ dis, int N) {
    int i = blockIdx.x * blockDim.x + threadIdx.x;
    if (i < N) dis[i] = rsqrtf((float)deg[i]);
}

__global__ void scan1_kernel(const int* __restrict__ deg, int* __restrict__ rowptr,
                             int* __restrict__ bsums, int N) {
    __shared__ int sm[256];
    int i = blockIdx.x * 256 + threadIdx.x;
    int v = (i < N) ? (deg[i] - 1) : 0;
    sm[threadIdx.x] = v;
    __syncthreads();
    int s = v;
    for (int off = 1; off < 256; off <<= 1) {
        int t = 0;
        if ((int)threadIdx.x >= off) t = sm[threadIdx.x - off];
        __syncthreads();
        s += t;
        sm[threadIdx.x] = s;
        __syncthreads();
    }
    if (i < N) rowptr[i] = s - v;
    if (threadIdx.x == 255) bsums[blockIdx.x] = s;
}

__global__ void scan2_kernel(const int* __restrict__ bsums, int* __restrict__ boff, int NB) {
    __shared__ int sm[256];
    int t = threadIdx.x;
    int v = (t < NB) ? bsums[t] : 0;
    sm[t] = v;
    __syncthreads();
    int s = v;
    for (int off = 1; off < 256; off <<= 1) {
        int x = 0;
        if (t >= off) x = sm[t - off];
        __syncthreads();
        s += x;
        sm[t] = s;
        __syncthreads();
    }
    boff[t] = s - v;
}

__global__ void scan3_kernel(int* __restrict__ rowptr, const int* __restrict__ boff, int N, int E) {
    int i = blockIdx.x * 256 + threadIdx.x;
    if (i < N) rowptr[i] += boff[blockIdx.x];
    if (blockIdx.x == 0 && threadIdx.x == 0) rowptr[N] = E;
}

// CSR entry = (src, norm) packed in one int2 -> single 8B scattered store per edge
__global__ void fill_kernel(const int* __restrict__ src, const int* __restrict__ dst,
                            const int* __restrict__ rowptr, int* __restrict__ fill,
                            const float* __restrict__ dis,
                            int2* __restrict__ csr, int E) {
    int i = blockIdx.x * blockDim.x + threadIdx.x;
    if (i >= E) return;
    int s = src[i], d = dst[i];
    int pos = atomicAdd(&fill[d], 1);
    int idx = rowptr[d] + pos;
    float nm = dis[s] * dis[d];
    csr[idx] = make_int2(s, __float_as_int(nm));
}

// ---------------- dtype prep ----------------

__global__ void x2b_kernel(const float* __restrict__ X, ushort_t* __restrict__ Xb, int n8) {
    int i = blockIdx.x * 256 + threadIdx.x;
    if (i >= n8) return;
    const float4* X4 = reinterpret_cast<const float4*>(X);
    float4 a = X4[i * 2], b = X4[i * 2 + 1];
    ushort4 lo, hi;
    lo.x = f2b(a.x); lo.y = f2b(a.y); lo.z = f2b(a.z); lo.w = f2b(a.w);
    hi.x = f2b(b.x); hi.y = f2b(b.y); hi.z = f2b(b.z); hi.w = f2b(b.w);
    reinterpret_cast<ushort4*>(Xb)[i * 2]     = lo;
    reinterpret_cast<ushort4*>(Xb)[i * 2 + 1] = hi;
}

// Pack W [K][256] f32 into MFMA B-fragment layout: [K/32][16 ct][64 lane][8]
__global__ void packW_kernel(const float* __restrict__ W, ushort_t* __restrict__ Bp, int total) {
    int idx = blockIdx.x * 256 + threadIdx.x;
    if (idx >= total) return;
    int j    = idx & 7;
    int lane = (idx >> 3) & 63;
    int ct   = (idx >> 9) & 15;
    int kk   = idx >> 13;
    int k    = kk * 32 + (lane >> 4) * 8 + j;
    int col  = ct * 16 + (lane & 15);
    Bp[idx] = f2b(W[(size_t)k * 256 + col]);
}

// ------------- aggregation, bf16, 128 feats: 4 nodes/wave, 16 lanes x ushort8 per row -------------

__global__ __launch_bounds__(256) void aggb_128_kernel(const ushort_t* __restrict__ Xb,
                                                       const int* __restrict__ rowptr,
                                                       const int2* __restrict__ csr,
                                                       const float* __restrict__ dis,
                                                       ushort_t* __restrict__ Out, int N) {
    int sub  = threadIdx.x & 15;
    int node = blockIdx.x * 16 + (threadIdx.x >> 4);
    bool valid = node < N;
    int nd = valid ? node : N - 1;

    const u16x8* X8 = reinterpret_cast<const u16x8*>(Xb);   // row stride = 16
    float dn = dis[nd];
    float n0 = dn * dn;
    u16x8 sv = X8[(size_t)nd * 16 + sub];
    float acc[8];
#pragma unroll
    for (int t = 0; t < 8; ++t) acc[t] = b2f(sv[t]) * n0;

    int j = rowptr[nd], end = rowptr[nd + 1];
    for (; j + 4 <= end; j += 4) {
        int2 e0 = csr[j],     e1 = csr[j + 1];
        int2 e2 = csr[j + 2], e3 = csr[j + 3];
        float m0 = __int_as_float(e0.y), m1 = __int_as_float(e1.y);
        float m2 = __int_as_float(e2.y), m3 = __int_as_float(e3.y);
        u16x8 v0 = X8[(size_t)e0.x * 16 + sub];
        u16x8 v1 = X8[(size_t)e1.x * 16 + sub];
        u16x8 v2 = X8[(size_t)e2.x * 16 + sub];
        u16x8 v3 = X8[(size_t)e3.x * 16 + sub];
#pragma unroll
        for (int t = 0; t < 8; ++t) {
            acc[t] = fmaf(b2f(v0[t]), m0, acc[t]);
            acc[t] = fmaf(b2f(v1[t]), m1, acc[t]);
            acc[t] = fmaf(b2f(v2[t]), m2, acc[t]);
            acc[t] = fmaf(b2f(v3[t]), m3, acc[t]);
        }
    }
    for (; j < end; ++j) {
        int2 e = csr[j];
        float m = __int_as_float(e.y);
        u16x8 v = X8[(size_t)e.x * 16 + sub];
#pragma unroll
        for (int t = 0; t < 8; ++t) acc[t] = fmaf(b2f(v[t]), m, acc[t]);
    }
    if (valid) {
        u16x8 o;
#pragma unroll
        for (int t = 0; t < 8; ++t) o[t] = f2b(acc[t]);
        reinterpret_cast<u16x8*>(Out)[(size_t)node * 16 + sub] = o;
    }
}

// ------------- aggregation over fp8 H1 table, 256 feats: wave/node, lane owns 4 fp8 -------------

#define ACC4(w, m)                                                          \
    {                                                                       \
        f32x2 lo_ = __builtin_amdgcn_cvt_pk_f32_fp8((int)(w), false);       \
        f32x2 hi_ = __builtin_amdgcn_cvt_pk_f32_fp8((int)(w), true);        \
        a0 = fmaf(lo_[0], (m), a0); a1 = fmaf(lo_[1], (m), a1);             \
        a2 = fmaf(hi_[0], (m), a2); a3 = fmaf(hi_[1], (m), a3);             \
    }

__global__ __launch_bounds__(256) void aggf8_256_kernel(const uchar_t* __restrict__ H8,
                                                        const int* __restrict__ rowptr,
                                                        const int2* __restrict__ csr,
                                                        const float* __restrict__ dis,
                                                        ushort_t* __restrict__ Out, int N) {
    int lane = threadIdx.x & 63;
    int node = blockIdx.x * (blockDim.x >> 6) + (threadIdx.x >> 6);
    if (node >= N) return;

    const uint_t* T = reinterpret_cast<const uint_t*>(H8);   // row = 64 dwords (256 fp8)
    float dn = dis[node];
    float n0 = dn * dn;
    float a0, a1, a2, a3;
    {
        uint_t w = T[(size_t)node * 64 + lane];
        f32x2 lo_ = __builtin_amdgcn_cvt_pk_f32_fp8((int)w, false);
        f32x2 hi_ = __builtin_amdgcn_cvt_pk_f32_fp8((int)w, true);
        a0 = lo_[0] * n0; a1 = lo_[1] * n0; a2 = hi_[0] * n0; a3 = hi_[1] * n0;
    }

    int j = rowptr[node], end = rowptr[node + 1];
    for (; j + 8 <= end; j += 8) {
        int2 e0 = csr[j],     e1 = csr[j + 1];
        int2 e2 = csr[j + 2], e3 = csr[j + 3];
        int2 e4 = csr[j + 4], e5 = csr[j + 5];
        int2 e6 = csr[j + 6], e7 = csr[j + 7];
        uint_t w0 = T[(size_t)e0.x * 64 + lane];
        uint_t w1 = T[(size_t)e1.x * 64 + lane];
        uint_t w2 = T[(size_t)e2.x * 64 + lane];
        uint_t w3 = T[(size_t)e3.x * 64 + lane];
        uint_t w4 = T[(size_t)e4.x * 64 + lane];
        uint_t w5 = T[(size_t)e5.x * 64 + lane];
        uint_t w6 = T[(size_t)e6.x * 64 + lane];
        uint_t w7 = T[(size_t)e7.x * 64 + lane];
        ACC4(w0, __int_as_float(e0.y)) ACC4(w1, __int_as_float(e1.y))
        ACC4(w2, __int_as_float(e2.y)) ACC4(w3, __int_as_float(e3.y))
        ACC4(w4, __int_as_float(e4.y)) ACC4(w5, __int_as_float(e5.y))
        ACC4(w6, __int_as_float(e6.y)) ACC4(w7, __int_as_float(e7.y))
    }
    for (; j + 4 <= end; j += 4) {
        int2 e0 = csr[j],     e1 = csr[j + 1];
        int2 e2 = csr[j + 2], e3 = csr[j + 3];
        uint_t w0 = T[(size_t)e0.x * 64 + lane];
        uint_t w1 = T[(size_t)e1.x * 64 + lane];
        uint_t w2 = T[(size_t)e2.x * 64 + lane];
        uint_t w3 = T[(size_t)e3.x * 64 + lane];
        ACC4(w0, __int_as_float(e0.y)) ACC4(w1, __int_as_float(e1.y))
        ACC4(w2, __int_as_float(e2.y)) ACC4(w3, __int_as_float(e3.y))
    }
    for (; j < end; ++j) {
        int2 e = csr[j];
        uint_t w = T[(size_t)e.x * 64 + lane];
        ACC4(w, __int_as_float(e.y))
    }

    ushort4 o;
    o.x = f2b(a0); o.y = f2b(a1); o.z = f2b(a2); o.w = f2b(a3);
    reinterpret_cast<ushort4*>(Out)[(size_t)node * 64 + lane] = o;   // bf16 [N,256]
}

// ---------------- MFMA GEMM: A[N,K] bf16 @ Wp (packed) -> 256 cols ----------------
// MODE 1: OutB8 = fp8e4m3(relu(acc + bias))  [N,256] row-major (gather table)
// MODE 2: OutF  = relu(acc + bias) . W3      [N] f32

template <int K, int MODE>
__global__ __launch_bounds__(256) void mfma_gemm_kernel(const ushort_t* __restrict__ A,
                                                        const ushort_t* __restrict__ Bp,
                                                        const float* __restrict__ bias,
                                                        const float* __restrict__ W3,
                                                        float* __restrict__ OutF,
                                                        uchar_t* __restrict__ OutB8, int N) {
    int wid  = threadIdx.x >> 6;
    int lane = threadIdx.x & 63;
    int row0 = blockIdx.x * 64 + wid * 16;

    int ar = row0 + (lane & 15);
    if (ar >= N) ar = N - 1;                 // clamp; stores are guarded below
    const ushort_t* arow = A + (size_t)ar * K + (lane >> 4) * 8;

    f32x4 acc[16];
#pragma unroll
    for (int ct = 0; ct < 16; ++ct) acc[ct] = (f32x4){0.f, 0.f, 0.f, 0.f};

    const bf16x8* Bv = reinterpret_cast<const bf16x8*>(Bp);
#pragma unroll
    for (int kk = 0; kk < K / 32; ++kk) {
        bf16x8 a = *reinterpret_cast<const bf16x8*>(arow + kk * 32);
        const bf16x8* bbase = Bv + (size_t)kk * 1024 + lane;
#pragma unroll
        for (int ct = 0; ct < 16; ++ct) {
            bf16x8 b = bbase[ct * 64];
            acc[ct] = __builtin_amdgcn_mfma_f32_16x16x32_bf16(a, b, acc[ct], 0, 0, 0);
        }
    }

    int orow = row0 + (lane >> 4) * 4;
    int ocol = lane & 15;

    if (MODE == 1) {
#pragma unroll
        for (int r = 0; r < 4; ++r) {
            int gr = orow + r;
            if (gr < N) {
#pragma unroll
                for (int ct = 0; ct < 16; ++ct) {
                    float v = fmaxf(acc[ct][r] + bias[ct * 16 + ocol], 0.f);
                    OutB8[(size_t)gr * 256 + ct * 16 + ocol] = f2fp8(v);
                }
            }
        }
    } else {
#pragma unroll
        for (int r = 0; r < 4; ++r) {
            float p = 0.f;
#pragma unroll
            for (int ct = 0; ct < 16; ++ct) {
                float v = fmaxf(acc[ct][r] + bias[ct * 16 + ocol], 0.f);
                p = fmaf(v, W3[ct * 16 + ocol], p);
            }
            p += __shfl_xor(p, 1);
            p += __shfl_xor(p, 2);
            p += __shfl_xor(p, 4);
            p += __shfl_xor(p, 8);
            int gr = orow + r;
            if (ocol == 0 && gr < N) OutF[gr] = p;
        }
    }
}

// ------------- final 1-wide aggregation + sigmoid (unrolled) -------------

__global__ void agg1_kernel(const float* __restrict__ c, const int* __restrict__ rowptr,
                            const int2* __restrict__ csr,
                            const float* __restrict__ dis, const float* __restrict__ b3,
                            float* __restrict__ out, int N) {
    int i = blockIdx.x * blockDim.x + threadIdx.x;
    if (i >= N) return;
    float dn = dis[i];
    float acc = c[i] * dn * dn;
    int j = rowptr[i], end = rowptr[i + 1];
    for (; j + 4 <= end; j += 4) {
        int2 e0 = csr[j],     e1 = csr[j + 1];
        int2 e2 = csr[j + 2], e3 = csr[j + 3];
        acc = fmaf(c[e0.x], __int_as_float(e0.y), acc);
        acc = fmaf(c[e1.x], __int_as_float(e1.y), acc);
        acc = fmaf(c[e2.x], __int_as_float(e2.y), acc);
        acc = fmaf(c[e3.x], __int_as_float(e3.y), acc);
    }
    for (; j < end; ++j) {
        int2 e = csr[j];
        acc = fmaf(c[e.x], __int_as_float(e.y), acc);
    }
    acc += b3[0];
    out[i] = 1.0f / (1.0f + expf(-acc));
}

// ---------------- launch ----------------

extern "C" void kernel_launch(void* const* d_in, const int* in_sizes, int n_in,
                              void* d_out, int out_size, void* d_ws, size_t ws_size,
                              hipStream_t stream) {
    const float* x  = (const float*)d_in[0];
    const int*   ei = (const int*)d_in[1];
    const float* W1 = (const float*)d_in[2];
    const float* b1 = (const float*)d_in[3];
    const float* W2 = (const float*)d_in[4];
    const float* b2 = (const float*)d_in[5];
    const float* W3 = (const float*)d_in[6];
    const float* b3 = (const float*)d_in[7];

    int N = in_sizes[0] / NF;      // 50000
    int E = in_sizes[1] / 2;       // 640000
    const int* src = ei;
    const int* dst = ei + E;

    char* ws = (char*)d_ws;
    auto alloc = [&](size_t bytes) -> void* {
        void* p = (void*)ws;
        ws += (bytes + 255) & ~(size_t)255;
        return p;
    };
    int*      deg      = (int*)alloc((size_t)N * 4);
    int*      fill     = (int*)alloc((size_t)N * 4);
    float*    dis      = (float*)alloc((size_t)N * 4);
    int*      rowptr   = (int*)alloc((size_t)(N + 1) * 4);
    int*      bsums    = (int*)alloc(1024);
    int*      boff     = (int*)alloc(1024);
    int2*     csr      = (int2*)alloc((size_t)E * 8);            // (src, norm) pairs
    ushort_t* Xb       = (ushort_t*)alloc((size_t)N * NF * 2);   // X bf16         [N,128]
    ushort_t* bufAXb   = (ushort_t*)alloc((size_t)N * NF * 2);   // Â·X bf16       [N,128]
    uchar_t*  bufH1    = (uchar_t*)alloc((size_t)N * NH);        // H1 fp8 e4m3    [N,256]
    ushort_t* bufGb    = (ushort_t*)alloc((size_t)N * NH * 2);   // Â·H1 bf16      [N,256]
    ushort_t* W1p      = (ushort_t*)alloc((size_t)NF * NH * 2);  // packed W1
    ushort_t* W2p      = (ushort_t*)alloc((size_t)NH * NH * 2);  // packed W2
    float*    bufC     = (float*)alloc((size_t)N * 4);           // H2·W3 [N] f32
    (void)ws_size; (void)n_in; (void)out_size;

    int nbN = (N + 255) / 256;           // 196
    int nbE = (E + 255) / 256;           // 2500

    // graph prep
    init_kernel<<<nbN, 256, 0, stream>>>(deg, fill, N);
    count_kernel<<<nbE, 256, 0, stream>>>(dst, deg, E);
    dis_kernel<<<nbN, 256, 0, stream>>>(deg, dis, N);
    scan1_kernel<<<nbN, 256, 0, stream>>>(deg, rowptr, bsums, N);
    scan2_kernel<<<1, 256, 0, stream>>>(bsums, boff, nbN);
    scan3_kernel<<<nbN, 256, 0, stream>>>(rowptr, boff, N, E);
    fill_kernel<<<nbE, 256, 0, stream>>>(src, dst, rowptr, fill, dis, csr, E);

    // dtype prep
    int n8 = N * NF / 8;
    x2b_kernel<<<(n8 + 255) / 256, 256, 0, stream>>>(x, Xb, n8);
    packW_kernel<<<(NF * NH + 255) / 256, 256, 0, stream>>>(W1, W1p, NF * NH);
    packW_kernel<<<(NH * NH + 255) / 256, 256, 0, stream>>>(W2, W2p, NH * NH);

    int nbA128 = (N + 15) / 16;          // 3125 (16 nodes/block)
    int nbA256 = (N + 3) / 4;            // 12500 (wave per node, 4/block)
    int nbM = (N + 63) / 64;             // 782

    // layer 1: AXb = Â·Xb ; H1(fp8) = fp8(relu(AXb@W1 + b1))
    aggb_128_kernel<<<nbA128, 256, 0, stream>>>(Xb, rowptr, csr, dis, bufAXb, N);
    mfma_gemm_kernel<NF, 1><<<nbM, 256, 0, stream>>>(bufAXb, W1p, b1, nullptr, nullptr, bufH1, N);
    // layer 2: Gb(bf16) = Â·H1(fp8) ; C = relu(Gb@W2 + b2)·W3
    aggf8_256_kernel<<<nbA256, 256, 0, stream>>>(bufH1, rowptr, csr, dis, bufGb, N);
    mfma_gemm_kernel<NH, 2><<<nbM, 256, 0, stream>>>(bufGb, W2p, b2, W3, bufC, nullptr, N);
    // layer 3: out = sigmoid(Â·C + b3)
    agg1_kernel<<<nbN, 256, 0, stream>>>(bufC, rowptr, csr, dis, b3, (float*)d_out, N);
}

// Round 15
// 183.654 us; speedup vs baseline: 2.3872x; 1.0614x over previous
//
#include <hip/hip_runtime.h>
#include <math.h>

#define NF 128
#define NH 256

typedef unsigned short ushort_t;
typedef unsigned char uchar_t;
typedef unsigned int uint_t;
typedef __attribute__((ext_vector_type(8))) short bf16x8;
typedef __attribute__((ext_vector_type(8))) unsigned short u16x8;
typedef __attribute__((ext_vector_type(4))) float f32x4;
typedef __attribute__((ext_vector_type(2))) float f32x2;

__device__ __forceinline__ float b2f(ushort_t h) {
    return __uint_as_float((unsigned int)h << 16);
}
__device__ __forceinline__ ushort_t f2b(float f) {
    unsigned int u = __float_as_uint(f);
    unsigned int r = (u + 0x7FFF + ((u >> 16) & 1)) >> 16;   // RNE
    return (ushort_t)r;
}
// f32 -> OCP fp8 e4m3 (RNE, saturating) via HW cvt
__device__ __forceinline__ uchar_t f2fp8(float f) {
    int p = __builtin_amdgcn_cvt_pk_fp8_f32(f, f, 0, false);
    return (uchar_t)(p & 0xFF);
}

// ---------------- graph prep ----------------

__global__ void init_kernel(int* __restrict__ deg, int* __restrict__ fill, int N) {
    int i = blockIdx.x * blockDim.x + threadIdx.x;
    if (i < N) { deg[i] = 1; fill[i] = 0; }   // 1 = self-loop
}

__global__ void count_kernel(const int* __restrict__ dst, int* __restrict__ deg, int E) {
    int i = blockIdx.x * blockDim.x + threadIdx.x;
    if (i < E) atomicAdd(&deg[dst[i]], 1);
}

// scan of (deg-1) for rowptr + fused dis = rsqrt(deg)
__global__ void scan1_kernel(const int* __restrict__ deg, int* __restrict__ rowptr,
                             int* __restrict__ bsums, float* __restrict__ dis, int N) {
    __shared__ int sm[256];
    int i = blockIdx.x * 256 + threadIdx.x;
    int v = (i < N) ? (deg[i] - 1) : 0;
    sm[threadIdx.x] = v;
    __syncthreads();
    int s = v;
    for (int off = 1; off < 256; off <<= 1) {
        int t = 0;
        if ((int)threadIdx.x >= off) t = sm[threadIdx.x - off];
        __syncthreads();
        s += t;
        sm[threadIdx.x] = s;
        __syncthreads();
    }
    if (i < N) {
        rowptr[i] = s - v;
        dis[i] = rsqrtf((float)(v + 1));
    }
    if (threadIdx.x == 255) bsums[blockIdx.x] = s;
}

__global__ void scan2_kernel(const int* __restrict__ bsums, int* __restrict__ boff, int NB) {
    __shared__ int sm[256];
    int t = threadIdx.x;
    int v = (t < NB) ? bsums[t] : 0;
    sm[t] = v;
    __syncthreads();
    int s = v;
    for (int off = 1; off < 256; off <<= 1) {
        int x = 0;
        if (t >= off) x = sm[t - off];
        __syncthreads();
        s += x;
        sm[t] = s;
        __syncthreads();
    }
    boff[t] = s - v;
}

__global__ void scan3_kernel(int* __restrict__ rowptr, const int* __restrict__ boff, int N, int E) {
    int i = blockIdx.x * 256 + threadIdx.x;
    if (i < N) rowptr[i] += boff[blockIdx.x];
    if (blockIdx.x == 0 && threadIdx.x == 0) rowptr[N] = E;
}

// CSR entry = (src, norm) packed in one int2 -> single 8B scattered store per edge
__global__ void fill_kernel(const int* __restrict__ src, const int* __restrict__ dst,
                            const int* __restrict__ rowptr, int* __restrict__ fill,
                            const float* __restrict__ dis,
                            int2* __restrict__ csr, int E) {
    int i = blockIdx.x * blockDim.x + threadIdx.x;
    if (i >= E) return;
    int s = src[i], d = dst[i];
    int pos = atomicAdd(&fill[d], 1);
    int idx = rowptr[d] + pos;
    float nm = dis[s] * dis[d];
    csr[idx] = make_int2(s, __float_as_int(nm));
}

// ---------------- fused dtype prep: X->fp8 table + packW1 + packW2 ----------------
// section A: i in [0, n8)           : convert X[8i..8i+8) f32 -> fp8
// section B: i in [n8, n8+w1n)      : pack W1 (K=128)
// section C: i in [n8+w1n, total)   : pack W2 (K=256)

__device__ __forceinline__ void packW_one(const float* __restrict__ W, ushort_t* __restrict__ Bp,
                                          int idx) {
    int j    = idx & 7;
    int lane = (idx >> 3) & 63;
    int ct   = (idx >> 9) & 15;
    int kk   = idx >> 13;
    int k    = kk * 32 + (lane >> 4) * 8 + j;
    int col  = ct * 16 + (lane & 15);
    Bp[idx] = f2b(W[(size_t)k * 256 + col]);
}

__global__ void prep_misc_kernel(const float* __restrict__ X, uchar_t* __restrict__ X8,
                                 const float* __restrict__ W1, ushort_t* __restrict__ W1p,
                                 const float* __restrict__ W2, ushort_t* __restrict__ W2p,
                                 int n8, int w1n, int w2n) {
    int i = blockIdx.x * 256 + threadIdx.x;
    if (i < n8) {
        const float4* X4 = reinterpret_cast<const float4*>(X);
        float4 a = X4[i * 2], b = X4[i * 2 + 1];
        uint_t lo = 0, hi = 0;
        lo = (uint_t)__builtin_amdgcn_cvt_pk_fp8_f32(a.x, a.y, (int)lo, false);
        lo = (uint_t)__builtin_amdgcn_cvt_pk_fp8_f32(a.z, a.w, (int)lo, true);
        hi = (uint_t)__builtin_amdgcn_cvt_pk_fp8_f32(b.x, b.y, (int)hi, false);
        hi = (uint_t)__builtin_amdgcn_cvt_pk_fp8_f32(b.z, b.w, (int)hi, true);
        reinterpret_cast<uint2*>(X8)[i] = make_uint2(lo, hi);
    } else if (i < n8 + w1n) {
        packW_one(W1, W1p, i - n8);
    } else if (i < n8 + w1n + w2n) {
        packW_one(W2, W2p, i - n8 - w1n);
    }
}

// ---------------- fp8 decode helpers ----------------

#define ACC4(w, m)                                                          \
    {                                                                       \
        f32x2 lo_ = __builtin_amdgcn_cvt_pk_f32_fp8((int)(w), false);       \
        f32x2 hi_ = __builtin_amdgcn_cvt_pk_f32_fp8((int)(w), true);        \
        a0 = fmaf(lo_[0], (m), a0); a1 = fmaf(lo_[1], (m), a1);             \
        a2 = fmaf(hi_[0], (m), a2); a3 = fmaf(hi_[1], (m), a3);             \
    }

#define ACC8(w2v, m)                                                        \
    {                                                                       \
        f32x2 l0_ = __builtin_amdgcn_cvt_pk_f32_fp8((int)(w2v).x, false);   \
        f32x2 h0_ = __builtin_amdgcn_cvt_pk_f32_fp8((int)(w2v).x, true);    \
        f32x2 l1_ = __builtin_amdgcn_cvt_pk_f32_fp8((int)(w2v).y, false);   \
        f32x2 h1_ = __builtin_amdgcn_cvt_pk_f32_fp8((int)(w2v).y, true);    \
        acc[0] = fmaf(l0_[0], (m), acc[0]); acc[1] = fmaf(l0_[1], (m), acc[1]); \
        acc[2] = fmaf(h0_[0], (m), acc[2]); acc[3] = fmaf(h0_[1], (m), acc[3]); \
        acc[4] = fmaf(l1_[0], (m), acc[4]); acc[5] = fmaf(l1_[1], (m), acc[5]); \
        acc[6] = fmaf(h1_[0], (m), acc[6]); acc[7] = fmaf(h1_[1], (m), acc[7]); \
    }

// ------------- aggregation over fp8 X table, 128 feats: 4 nodes/wave, 16 lanes x uint2 -------------
// Out (bf16) = sum_e fp8dec(X[src_e])*norm_e + fp8dec(X[n])*dis[n]^2

__global__ __launch_bounds__(256) void aggf8_128_kernel(const uchar_t* __restrict__ X8,
                                                        const int* __restrict__ rowptr,
                                                        const int2* __restrict__ csr,
                                                        const float* __restrict__ dis,
                                                        ushort_t* __restrict__ Out, int N) {
    int sub  = threadIdx.x & 15;
    int node = blockIdx.x * 16 + (threadIdx.x >> 4);
    bool valid = node < N;
    int nd = valid ? node : N - 1;

    const uint2* T = reinterpret_cast<const uint2*>(X8);    // row stride = 16 uint2 (128 fp8)
    float dn = dis[nd];
    float n0 = dn * dn;
    float acc[8];
    {
        uint2 w = T[(size_t)nd * 16 + sub];
        f32x2 l0_ = __builtin_amdgcn_cvt_pk_f32_fp8((int)w.x, false);
        f32x2 h0_ = __builtin_amdgcn_cvt_pk_f32_fp8((int)w.x, true);
        f32x2 l1_ = __builtin_amdgcn_cvt_pk_f32_fp8((int)w.y, false);
        f32x2 h1_ = __builtin_amdgcn_cvt_pk_f32_fp8((int)w.y, true);
        acc[0] = l0_[0] * n0; acc[1] = l0_[1] * n0;
        acc[2] = h0_[0] * n0; acc[3] = h0_[1] * n0;
        acc[4] = l1_[0] * n0; acc[5] = l1_[1] * n0;
        acc[6] = h1_[0] * n0; acc[7] = h1_[1] * n0;
    }

    int j = rowptr[nd], end = rowptr[nd + 1];
    for (; j + 4 <= end; j += 4) {
        int2 e0 = csr[j],     e1 = csr[j + 1];
        int2 e2 = csr[j + 2], e3 = csr[j + 3];
        uint2 w0 = T[(size_t)e0.x * 16 + sub];
        uint2 w1 = T[(size_t)e1.x * 16 + sub];
        uint2 w2 = T[(size_t)e2.x * 16 + sub];
        uint2 w3 = T[(size_t)e3.x * 16 + sub];
        ACC8(w0, __int_as_float(e0.y)) ACC8(w1, __int_as_float(e1.y))
        ACC8(w2, __int_as_float(e2.y)) ACC8(w3, __int_as_float(e3.y))
    }
    for (; j < end; ++j) {
        int2 e = csr[j];
        uint2 w = T[(size_t)e.x * 16 + sub];
        ACC8(w, __int_as_float(e.y))
    }
    if (valid) {
        u16x8 o;
#pragma unroll
        for (int t = 0; t < 8; ++t) o[t] = f2b(acc[t]);
        reinterpret_cast<u16x8*>(Out)[(size_t)node * 16 + sub] = o;   // bf16 [N,128]
    }
}

// ------------- aggregation over fp8 H1 table, 256 feats: wave/node, lane owns 4 fp8 -------------

__global__ __launch_bounds__(256) void aggf8_256_kernel(const uchar_t* __restrict__ H8,
                                                        const int* __restrict__ rowptr,
                                                        const int2* __restrict__ csr,
                                                        const float* __restrict__ dis,
                                                        ushort_t* __restrict__ Out, int N) {
    int lane = threadIdx.x & 63;
    int node = blockIdx.x * (blockDim.x >> 6) + (threadIdx.x >> 6);
    if (node >= N) return;

    const uint_t* T = reinterpret_cast<const uint_t*>(H8);   // row = 64 dwords (256 fp8)
    float dn = dis[node];
    float n0 = dn * dn;
    float a0, a1, a2, a3;
    {
        uint_t w = T[(size_t)node * 64 + lane];
        f32x2 lo_ = __builtin_amdgcn_cvt_pk_f32_fp8((int)w, false);
        f32x2 hi_ = __builtin_amdgcn_cvt_pk_f32_fp8((int)w, true);
        a0 = lo_[0] * n0; a1 = lo_[1] * n0; a2 = hi_[0] * n0; a3 = hi_[1] * n0;
    }

    int j = rowptr[node], end = rowptr[node + 1];
    for (; j + 8 <= end; j += 8) {
        int2 e0 = csr[j],     e1 = csr[j + 1];
        int2 e2 = csr[j + 2], e3 = csr[j + 3];
        int2 e4 = csr[j + 4], e5 = csr[j + 5];
        int2 e6 = csr[j + 6], e7 = csr[j + 7];
        uint_t w0 = T[(size_t)e0.x * 64 + lane];
        uint_t w1 = T[(size_t)e1.x * 64 + lane];
        uint_t w2 = T[(size_t)e2.x * 64 + lane];
        uint_t w3 = T[(size_t)e3.x * 64 + lane];
        uint_t w4 = T[(size_t)e4.x * 64 + lane];
        uint_t w5 = T[(size_t)e5.x * 64 + lane];
        uint_t w6 = T[(size_t)e6.x * 64 + lane];
        uint_t w7 = T[(size_t)e7.x * 64 + lane];
        ACC4(w0, __int_as_float(e0.y)) ACC4(w1, __int_as_float(e1.y))
        ACC4(w2, __int_as_float(e2.y)) ACC4(w3, __int_as_float(e3.y))
        ACC4(w4, __int_as_float(e4.y)) ACC4(w5, __int_as_float(e5.y))
        ACC4(w6, __int_as_float(e6.y)) ACC4(w7, __int_as_float(e7.y))
    }
    for (; j + 4 <= end; j += 4) {
        int2 e0 = csr[j],     e1 = csr[j + 1];
        int2 e2 = csr[j + 2], e3 = csr[j + 3];
        uint_t w0 = T[(size_t)e0.x * 64 + lane];
        uint_t w1 = T[(size_t)e1.x * 64 + lane];
        uint_t w2 = T[(size_t)e2.x * 64 + lane];
        uint_t w3 = T[(size_t)e3.x * 64 + lane];
        ACC4(w0, __int_as_float(e0.y)) ACC4(w1, __int_as_float(e1.y))
        ACC4(w2, __int_as_float(e2.y)) ACC4(w3, __int_as_float(e3.y))
    }
    for (; j < end; ++j) {
        int2 e = csr[j];
        uint_t w = T[(size_t)e.x * 64 + lane];
        ACC4(w, __int_as_float(e.y))
    }

    ushort4 o;
    o.x = f2b(a0); o.y = f2b(a1); o.z = f2b(a2); o.w = f2b(a3);
    reinterpret_cast<ushort4*>(Out)[(size_t)node * 64 + lane] = o;   // bf16 [N,256]
}

// ---------------- MFMA GEMM: A[N,K] bf16 @ Wp (packed) -> 256 cols ----------------
// MODE 1: OutB8 = fp8e4m3(relu(acc + bias))  [N,256] row-major (gather table)
// MODE 2: OutF  = relu(acc + bias) . W3      [N] f32

template <int K, int MODE>
__global__ __launch_bounds__(256) void mfma_gemm_kernel(const ushort_t* __restrict__ A,
                                                        const ushort_t* __restrict__ Bp,
                                                        const float* __restrict__ bias,
                                                        const float* __restrict__ W3,
                                                        float* __restrict__ OutF,
                                                        uchar_t* __restrict__ OutB8, int N) {
    int wid  = threadIdx.x >> 6;
    int lane = threadIdx.x & 63;
    int row0 = blockIdx.x * 64 + wid * 16;

    int ar = row0 + (lane & 15);
    if (ar >= N) ar = N - 1;                 // clamp; stores are guarded below
    const ushort_t* arow = A + (size_t)ar * K + (lane >> 4) * 8;

    f32x4 acc[16];
#pragma unroll
    for (int ct = 0; ct < 16; ++ct) acc[ct] = (f32x4){0.f, 0.f, 0.f, 0.f};

    const bf16x8* Bv = reinterpret_cast<const bf16x8*>(Bp);
#pragma unroll
    for (int kk = 0; kk < K / 32; ++kk) {
        bf16x8 a = *reinterpret_cast<const bf16x8*>(arow + kk * 32);
        const bf16x8* bbase = Bv + (size_t)kk * 1024 + lane;
#pragma unroll
        for (int ct = 0; ct < 16; ++ct) {
            bf16x8 b = bbase[ct * 64];
            acc[ct] = __builtin_amdgcn_mfma_f32_16x16x32_bf16(a, b, acc[ct], 0, 0, 0);
        }
    }

    int orow = row0 + (lane >> 4) * 4;
    int ocol = lane & 15;

    if (MODE == 1) {
#pragma unroll
        for (int r = 0; r < 4; ++r) {
            int gr = orow + r;
            if (gr < N) {
#pragma unroll
                for (int ct = 0; ct < 16; ++ct) {
                    float v = fmaxf(acc[ct][r] + bias[ct * 16 + ocol], 0.f);
                    OutB8[(size_t)gr * 256 + ct * 16 + ocol] = f2fp8(v);
                }
            }
        }
    } else {
#pragma unroll
        for (int r = 0; r < 4; ++r) {
            float p = 0.f;
#pragma unroll
            for (int ct = 0; ct < 16; ++ct) {
                float v = fmaxf(acc[ct][r] + bias[ct * 16 + ocol], 0.f);
                p = fmaf(v, W3[ct * 16 + ocol], p);
            }
            p += __shfl_xor(p, 1);
            p += __shfl_xor(p, 2);
            p += __shfl_xor(p, 4);
            p += __shfl_xor(p, 8);
            int gr = orow + r;
            if (ocol == 0 && gr < N) OutF[gr] = p;
        }
    }
}

// ------------- final 1-wide aggregation + sigmoid (unrolled) -------------

__global__ void agg1_kernel(const float* __restrict__ c, const int* __restrict__ rowptr,
                            const int2* __restrict__ csr,
                            const float* __restrict__ dis, const float* __restrict__ b3,
                            float* __restrict__ out, int N) {
    int i = blockIdx.x * blockDim.x + threadIdx.x;
    if (i >= N) return;
    float dn = dis[i];
    float acc = c[i] * dn * dn;
    int j = rowptr[i], end = rowptr[i + 1];
    for (; j + 4 <= end; j += 4) {
        int2 e0 = csr[j],     e1 = csr[j + 1];
        int2 e2 = csr[j + 2], e3 = csr[j + 3];
        acc = fmaf(c[e0.x], __int_as_float(e0.y), acc);
        acc = fmaf(c[e1.x], __int_as_float(e1.y), acc);
        acc = fmaf(c[e2.x], __int_as_float(e2.y), acc);
        acc = fmaf(c[e3.x], __int_as_float(e3.y), acc);
    }
    for (; j < end; ++j) {
        int2 e = csr[j];
        acc = fmaf(c[e.x], __int_as_float(e.y), acc);
    }
    acc += b3[0];
    out[i] = 1.0f / (1.0f + expf(-acc));
}

// ---------------- launch ----------------

extern "C" void kernel_launch(void* const* d_in, const int* in_sizes, int n_in,
                              void* d_out, int out_size, void* d_ws, size_t ws_size,
                              hipStream_t stream) {
    const float* x  = (const float*)d_in[0];
    const int*   ei = (const int*)d_in[1];
    const float* W1 = (const float*)d_in[2];
    const float* b1 = (const float*)d_in[3];
    const float* W2 = (const float*)d_in[4];
    const float* b2 = (const float*)d_in[5];
    const float* W3 = (const float*)d_in[6];
    const float* b3 = (const float*)d_in[7];

    int N = in_sizes[0] / NF;      // 50000
    int E = in_sizes[1] / 2;       // 640000
    const int* src = ei;
    const int* dst = ei + E;

    char* ws = (char*)d_ws;
    auto alloc = [&](size_t bytes) -> void* {
        void* p = (void*)ws;
        ws += (bytes + 255) & ~(size_t)255;
        return p;
    };
    int*      deg      = (int*)alloc((size_t)N * 4);
    int*      fill     = (int*)alloc((size_t)N * 4);
    float*    dis      = (float*)alloc((size_t)N * 4);
    int*      rowptr   = (int*)alloc((size_t)(N + 1) * 4);
    int*      bsums    = (int*)alloc(1024);
    int*      boff     = (int*)alloc(1024);
    int2*     csr      = (int2*)alloc((size_t)E * 8);            // (src, norm) pairs
    uchar_t*  Xf8      = (uchar_t*)alloc((size_t)N * NF);        // X fp8          [N,128]
    ushort_t* bufAXb   = (ushort_t*)alloc((size_t)N * NF * 2);   // Â·X bf16       [N,128]
    uchar_t*  bufH1    = (uchar_t*)alloc((size_t)N * NH);        // H1 fp8 e4m3    [N,256]
    ushort_t* bufGb    = (ushort_t*)alloc((size_t)N * NH * 2);   // Â·H1 bf16      [N,256]
    ushort_t* W1p      = (ushort_t*)alloc((size_t)NF * NH * 2);  // packed W1
    ushort_t* W2p      = (ushort_t*)alloc((size_t)NH * NH * 2);  // packed W2
    float*    bufC     = (float*)alloc((size_t)N * 4);           // H2·W3 [N] f32
    (void)ws_size; (void)n_in; (void)out_size;

    int nbN = (N + 255) / 256;           // 196
    int nbE = (E + 255) / 256;           // 2500

    // graph prep
    init_kernel<<<nbN, 256, 0, stream>>>(deg, fill, N);
    count_kernel<<<nbE, 256, 0, stream>>>(dst, deg, E);
    scan1_kernel<<<nbN, 256, 0, stream>>>(deg, rowptr, bsums, dis, N);
    scan2_kernel<<<1, 256, 0, stream>>>(bsums, boff, nbN);
    scan3_kernel<<<nbN, 256, 0, stream>>>(rowptr, boff, N, E);
    fill_kernel<<<nbE, 256, 0, stream>>>(src, dst, rowptr, fill, dis, csr, E);

    // fused dtype prep: X->fp8, packW1, packW2
    int n8  = N * NF / 8;                // 800000
    int w1n = NF * NH;                   // 32768
    int w2n = NH * NH;                   // 65536
    int tot = n8 + w1n + w2n;
    prep_misc_kernel<<<(tot + 255) / 256, 256, 0, stream>>>(x, Xf8, W1, W1p, W2, W2p,
                                                            n8, w1n, w2n);

    int nbA128 = (N + 15) / 16;          // 3125 (16 nodes/block)
    int nbA256 = (N + 3) / 4;            // 12500 (wave per node, 4/block)
    int nbM = (N + 63) / 64;             // 782

    // layer 1: AXb(bf16) = Â·X(fp8) ; H1(fp8) = fp8(relu(AXb@W1 + b1))
    aggf8_128_kernel<<<nbA128, 256, 0, stream>>>(Xf8, rowptr, csr, dis, bufAXb, N);
    mfma_gemm_kernel<NF, 1><<<nbM, 256, 0, stream>>>(bufAXb, W1p, b1, nullptr, nullptr, bufH1, N);
    // layer 2: Gb(bf16) = Â·H1(fp8) ; C = relu(Gb@W2 + b2)·W3
    aggf8_256_kernel<<<nbA256, 256, 0, stream>>>(bufH1, rowptr, csr, dis, bufGb, N);
    mfma_gemm_kernel<NH, 2><<<nbM, 256, 0, stream>>>(bufGb, W2p, b2, W3, bufC, nullptr, N);
    // layer 3: out = sigmoid(Â·C + b3)
    agg1_kernel<<<nbN, 256, 0, stream>>>(bufC, rowptr, csr, dis, b3, (float*)d_out, N);
}